// Round 8
// baseline (318.972 us; speedup 1.0000x reference)
//
#include <hip/hip_runtime.h>
#include <math.h>

// Problem constants
constexpr int CB = 8;      // batch
constexpr int CS = 1024;   // seq
constexpr int CD = 512;    // model dim
constexpr int CH = 8;      // heads
constexpr int CHD = 64;    // head dim
constexpr int CDFF = 2048; // ffn dim
constexpr int NROW = CB * CS;

typedef unsigned short u16;
typedef unsigned int u32;
typedef __attribute__((ext_vector_type(8))) short short8;
typedef __attribute__((ext_vector_type(8))) unsigned short ushort8v;
typedef __attribute__((ext_vector_type(4))) float floatx4;

__device__ inline u16 f2bf(float f) {
    union { float f; unsigned u; } v; v.f = f;
    unsigned u = v.u + 0x7FFFu + ((v.u >> 16) & 1u);  // RNE
    return (u16)(u >> 16);
}
__device__ inline float bf2f(u16 h) {
    union { unsigned u; float f; } v; v.u = ((unsigned)h) << 16;
    return v.f;
}

// tanh-form GELU: max abs err vs exact-erf GELU ~3e-4 -> ~1e-4 at output
__device__ inline float gelu_fast(float v) {
    float u = v * (1.0f + 0.044715f * v * v);
    float e = __expf(-1.5957691216057308f * u);
    return v / (1.0f + e);
}

// async global->LDS, 16B per lane; LDS dest is wave-uniform base + lane*16.
__device__ inline void gload16(const u16* g, u16* l) {
    __builtin_amdgcn_global_load_lds(
        (const __attribute__((address_space(1))) u32*)g,
        (__attribute__((address_space(3))) u32*)l, 16, 0, 0);
}

// raw workgroup barrier with compiler memory fences (no vmcnt drain!)
__device__ inline void barrier_raw() {
    asm volatile("" ::: "memory");
    __builtin_amdgcn_s_barrier();
    asm volatile("" ::: "memory");
}

// ---------------------------------------------------------------------------
// LayerNorm (+ optional embedding add). One block per row, 256 threads.
// ---------------------------------------------------------------------------
__global__ __launch_bounds__(256) void ln_kernel(
    const float* __restrict__ x, const int* __restrict__ ids,
    const float* __restrict__ emb,
    const float* __restrict__ g, const float* __restrict__ beta,
    float* __restrict__ xr_out, u16* __restrict__ xn_out)
{
    __shared__ float red1[4], red2[4];
    __shared__ float mu_s, ri_s;
    int row = blockIdx.x;
    int tid = threadIdx.x;
    int d0 = tid * 2;
    const float* xrow = x + (size_t)row * CD;
    float2 xv = *(const float2*)(xrow + d0);
    float v0 = xv.x, v1 = xv.y;
    if (emb) {
        int id = ids[row];
        float2 ev = *(const float2*)(emb + (size_t)id * CD + d0);
        v0 += ev.x; v1 += ev.y;
    }
    float s1 = v0 + v1;
    float s2 = v0 * v0 + v1 * v1;
    for (int off = 32; off > 0; off >>= 1) {
        s1 += __shfl_down(s1, off, 64);
        s2 += __shfl_down(s2, off, 64);
    }
    int wave = tid >> 6;
    if ((tid & 63) == 0) { red1[wave] = s1; red2[wave] = s2; }
    __syncthreads();
    if (tid == 0) {
        float t1 = red1[0] + red1[1] + red1[2] + red1[3];
        float t2 = red2[0] + red2[1] + red2[2] + red2[3];
        float mu = t1 / CD;
        float var = t2 / CD - mu * mu;
        mu_s = mu;
        ri_s = rsqrtf(var + 1e-5f);
    }
    __syncthreads();
    float mu = mu_s, ri = ri_s;
    if (xr_out) {
        float2 o; o.x = v0; o.y = v1;
        *(float2*)(xr_out + (size_t)row * CD + d0) = o;
    }
    float2 gv = *(const float2*)(g + d0);
    float2 bv = *(const float2*)(beta + d0);
    float n0 = (v0 - mu) * ri * gv.x + bv.x;
    float n1 = (v1 - mu) * ri * gv.y + bv.y;
    u32 pk = (u32)f2bf(n0) | ((u32)f2bf(n1) << 16);
    *(u32*)(xn_out + (size_t)row * CD + d0) = pk;
}

// ---------------------------------------------------------------------------
// fp32 -> bf16 convert for ALL 4 weight tensors in one launch.
// ---------------------------------------------------------------------------
__global__ __launch_bounds__(256) void conv4_kernel(
    const float* __restrict__ s0, const float* __restrict__ s1,
    const float* __restrict__ s2, const float* __restrict__ s3,
    u16* __restrict__ dst)
{
    size_t i = ((size_t)blockIdx.x * 256 + threadIdx.x) * 8;
    const float* src;
    size_t off;
    if (i < 786432)        { src = s0; off = i; }
    else if (i < 1048576)  { src = s1; off = i - 786432; }
    else if (i < 2097152)  { src = s2; off = i - 1048576; }
    else                   { src = s3; off = i - 2097152; }
    float4 a = *(const float4*)(src + off);
    float4 b = *(const float4*)(src + off + 4);
    ushort8v o;
    o[0] = f2bf(a.x); o[1] = f2bf(a.y); o[2] = f2bf(a.z); o[3] = f2bf(a.w);
    o[4] = f2bf(b.x); o[5] = f2bf(b.y); o[6] = f2bf(b.z); o[7] = f2bf(b.w);
    *(ushort8v*)(dst + i) = o;
}

// ---------------------------------------------------------------------------
// bf16 MFMA GEMM, 128x128 tile, COUNTED-VMCNT double-buffer (T4):
// per K-step: vmcnt(4) [older tile ready, newest 4 loads stay in flight] ->
// barrier -> compute buf[cur] -> barrier -> stage tile t+2 into buf[cur].
// Prefetch gets a FULL iteration to land instead of being drained.
// ---------------------------------------------------------------------------
template <int ACT, int RES, int OUTBF>
__global__ __launch_bounds__(256) void gemm_mfma(
    const u16* __restrict__ A, const u16* __restrict__ W,
    const float* __restrict__ bias, const float* __restrict__ res,
    void* __restrict__ Cout, int M, int N, int K)
{
    __shared__ u16 As[2][128 * 32];
    __shared__ u16 Bs[2][128 * 32];
    int t = threadIdx.x;
    int lane = t & 63;
    int w = t >> 6;
    int m0 = blockIdx.x * 128;
    int n0 = blockIdx.y * 128;
    int col = lane & 15;
    int quad = lane >> 4;
    int wm = w & 1, wn = w >> 1;
    int lo = w * 512;   // wave-local staging dest (elements)

    const u16* ag = A + (size_t)(m0 + (t >> 2)) * K + (t & 3) * 8;
    const u16* ag2 = ag + (size_t)64 * K;
    const u16* bg = W + (size_t)(n0 + (t >> 2)) * K + (t & 3) * 8;
    const u16* bg2 = bg + (size_t)64 * K;

    // prologue: stage K-tiles 0 and 1 (8 loads/wave in flight)
    gload16(ag, As[0] + lo);
    gload16(ag2, As[0] + 2048 + lo);
    gload16(bg, Bs[0] + lo);
    gload16(bg2, Bs[0] + 2048 + lo);
    gload16(ag + 32, As[1] + lo);
    gload16(ag2 + 32, As[1] + 2048 + lo);
    gload16(bg + 32, Bs[1] + lo);
    gload16(bg2 + 32, Bs[1] + 2048 + lo);

    floatx4 acc[4][4];
#pragma unroll
    for (int i = 0; i < 4; i++)
#pragma unroll
        for (int j = 0; j < 4; j++) acc[i][j] = (floatx4){0.f, 0.f, 0.f, 0.f};

    int nk = K >> 5;
    for (int kt = 0; kt < nk; kt++) {
        int cur = kt & 1;
        // wait: buf[cur] loads (older 4) done; newest 4 may stay in flight
        if (kt == nk - 1) asm volatile("s_waitcnt vmcnt(0)" ::: "memory");
        else              asm volatile("s_waitcnt vmcnt(4)" ::: "memory");
        barrier_raw();      // all waves' buf[cur] slices landed
        short8 af[4], bf[4];
#pragma unroll
        for (int mi = 0; mi < 4; mi++)
            af[mi] = *(const short8*)&As[cur][(wm * 64 + mi * 16 + col) * 32 + quad * 8];
#pragma unroll
        for (int ni = 0; ni < 4; ni++)
            bf[ni] = *(const short8*)&Bs[cur][(wn * 64 + ni * 16 + col) * 32 + quad * 8];
#pragma unroll
        for (int mi = 0; mi < 4; mi++)
#pragma unroll
            for (int ni = 0; ni < 4; ni++)
                acc[mi][ni] = __builtin_amdgcn_mfma_f32_16x16x32_bf16(
                    af[mi], bf[ni], acc[mi][ni], 0, 0, 0);
        barrier_raw();      // all waves done reading buf[cur]
        if (kt + 2 < nk) {  // stage tile kt+2 into buf[cur] (just released)
            int ko = (kt + 2) * 32;
            gload16(ag + ko, As[cur] + lo);
            gload16(ag2 + ko, As[cur] + 2048 + lo);
            gload16(bg + ko, Bs[cur] + lo);
            gload16(bg2 + ko, Bs[cur] + 2048 + lo);
        }
    }

#pragma unroll
    for (int mi = 0; mi < 4; mi++)
#pragma unroll
        for (int ni = 0; ni < 4; ni++) {
            int c = n0 + wn * 64 + ni * 16 + col;
            float bv = bias[c];
#pragma unroll
            for (int r = 0; r < 4; r++) {
                int m = m0 + wm * 64 + mi * 16 + quad * 4 + r;
                float v = acc[mi][ni][r] + bv;
                if (ACT == 1) v = gelu_fast(v);
                if (RES) v += res[(size_t)m * N + c];
                if (OUTBF) ((u16*)Cout)[(size_t)m * N + c] = f2bf(v);
                else       ((float*)Cout)[(size_t)m * N + c] = v;
            }
        }
}

// ---------------------------------------------------------------------------
// bf16 MFMA GEMM, 64x128 tile, counted-vmcnt double-buffer (T4)
// ---------------------------------------------------------------------------
template <int ACT, int RES, int OUTBF>
__global__ __launch_bounds__(256) void gemm_mfma64(
    const u16* __restrict__ A, const u16* __restrict__ W,
    const float* __restrict__ bias, const float* __restrict__ res,
    void* __restrict__ Cout, int M, int N, int K)
{
    __shared__ u16 As[2][64 * 32];
    __shared__ u16 Bs[2][128 * 32];
    int t = threadIdx.x;
    int lane = t & 63;
    int w = t >> 6;
    int m0 = blockIdx.x * 64;
    int n0 = blockIdx.y * 128;
    int col = lane & 15;
    int quad = lane >> 4;
    int lo = w * 512;

    const u16* ag = A + (size_t)(m0 + (t >> 2)) * K + (t & 3) * 8;
    const u16* bg = W + (size_t)(n0 + (t >> 2)) * K + (t & 3) * 8;
    const u16* bg2 = bg + (size_t)64 * K;

    // prologue: stage K-tiles 0 and 1 (6 loads/wave in flight)
    gload16(ag, As[0] + lo);
    gload16(bg, Bs[0] + lo);
    gload16(bg2, Bs[0] + 2048 + lo);
    gload16(ag + 32, As[1] + lo);
    gload16(bg + 32, Bs[1] + lo);
    gload16(bg2 + 32, Bs[1] + 2048 + lo);

    floatx4 acc[4][2];
#pragma unroll
    for (int i = 0; i < 4; i++)
#pragma unroll
        for (int j = 0; j < 2; j++) acc[i][j] = (floatx4){0.f, 0.f, 0.f, 0.f};

    int nk = K >> 5;
    for (int kt = 0; kt < nk; kt++) {
        int cur = kt & 1;
        if (kt == nk - 1) asm volatile("s_waitcnt vmcnt(0)" ::: "memory");
        else              asm volatile("s_waitcnt vmcnt(3)" ::: "memory");
        barrier_raw();
        short8 af[4], bf[2];
#pragma unroll
        for (int mi = 0; mi < 4; mi++)
            af[mi] = *(const short8*)&As[cur][(mi * 16 + col) * 32 + quad * 8];
#pragma unroll
        for (int ni = 0; ni < 2; ni++)
            bf[ni] = *(const short8*)&Bs[cur][(w * 32 + ni * 16 + col) * 32 + quad * 8];
#pragma unroll
        for (int mi = 0; mi < 4; mi++)
#pragma unroll
            for (int ni = 0; ni < 2; ni++)
                acc[mi][ni] = __builtin_amdgcn_mfma_f32_16x16x32_bf16(
                    af[mi], bf[ni], acc[mi][ni], 0, 0, 0);
        barrier_raw();
        if (kt + 2 < nk) {
            int ko = (kt + 2) * 32;
            gload16(ag + ko, As[cur] + lo);
            gload16(bg + ko, Bs[cur] + lo);
            gload16(bg2 + ko, Bs[cur] + 2048 + lo);
        }
    }

#pragma unroll
    for (int mi = 0; mi < 4; mi++)
#pragma unroll
        for (int ni = 0; ni < 2; ni++) {
            int c = n0 + w * 32 + ni * 16 + col;
            float bv = bias[c];
#pragma unroll
            for (int r = 0; r < 4; r++) {
                int m = m0 + mi * 16 + quad * 4 + r;
                float v = acc[mi][ni][r] + bv;
                if (ACT == 1) v = gelu_fast(v);
                if (RES) v += res[(size_t)m * N + c];
                if (OUTBF) ((u16*)Cout)[(size_t)m * N + c] = f2bf(v);
                else       ((float*)Cout)[(size_t)m * N + c] = v;
            }
        }
}

// ---------------------------------------------------------------------------
// V transpose: qkv cols 1024.. -> vt [b][h][d=64][S] (rows of S, 2KB)
// ---------------------------------------------------------------------------
__global__ __launch_bounds__(256) void vt_kernel(
    const u16* __restrict__ qkvb, u16* __restrict__ vt)
{
    __shared__ u16 tile[64][72];
    int b = blockIdx.x >> 4;
    int s0 = (blockIdx.x & 15) * 64;
    int h = blockIdx.y;
    int t = threadIdx.x;
    int r = t >> 2;
    int c0 = (t & 3) * 16;
    const u16* src = qkvb + (size_t)(b * CS + s0 + r) * 1536 + 2 * CD + h * CHD + c0;
    *(ushort8v*)&tile[r][c0] = *(const ushort8v*)src;
    *(ushort8v*)&tile[r][c0 + 8] = *(const ushort8v*)(src + 8);
    __syncthreads();
    u16* dst = vt + (((size_t)b * CH + h) * CHD + r) * CS + s0 + c0;
    ushort8v lo, hi;
#pragma unroll
    for (int j = 0; j < 8; j++) { lo[j] = tile[c0 + j][r]; hi[j] = tile[c0 + 8 + j][r]; }
    *(ushort8v*)dst = lo;
    *(ushort8v*)(dst + 8) = hi;
}

// ---------------------------------------------------------------------------
// attn_fused: QK + exp + PV in one staged kernel. Block = (b,h,64-q-tile),
// 512/half, 4 waves. (Kept __syncthreads: Se global stores in the QK phase
// make counted-vmcnt unreliable here — stores also tick vmcnt.)
// ---------------------------------------------------------------------------
__global__ __launch_bounds__(256, 2) void attn_fused_kernel(
    const u16* __restrict__ qkvb, const u16* __restrict__ vt,
    u16* __restrict__ Se, float* __restrict__ Lout,
    u16* __restrict__ ctx, int b0)
{
    __shared__ u16 Qs[2][64 * 32];      // [dsl][q][d-slice]        8 KB
    __shared__ u16 Ks[2][2][64 * 32];   // [buf][dsl][k][d-slice]  16 KB
    __shared__ u16 Vs[2][2][64 * 32];   // [buf][ksl][d][k-slice]  16 KB
    __shared__ u16 S[64][72];           // q x chunk-k (16B rows)  9.2 KB
    __shared__ float rs[4][4][16];

    int t = threadIdx.x;
    int lane = t & 63;
    int w = t >> 6;
    int col = lane & 15;
    int quad = lane >> 4;
    int bid = blockIdx.x;           // 512
    int xcd = bid & 7;
    int j = bid >> 3;               // 0..63
    int bhl = xcd * 4 + (j >> 4);   // 0..31
    int qt = j & 15;
    int lb = bhl >> 3, h = bhl & 7;
    int b = b0 + lb;
    int q0 = qt * 64;
    int bh = b * CH + h;
    size_t splane = (size_t)(lb * CH + h) * CS * CS;

    int srow = t >> 2;              // staged row 0..63
    int scol = (t & 3) * 8;         // within 32-elem slice

    const u16* ksrc0 = qkvb + (size_t)(b * CS + srow) * 1536 + CD + h * CHD + scol;
    const u16* vsrc0 = vt + ((size_t)bh * CHD + srow) * CS + scol;

    // prologue: Q (both d-slices) + K/V chunk 0
    {
        const u16* qsrc = qkvb + (size_t)(b * CS + q0 + srow) * 1536 + h * CHD + scol;
        gload16(qsrc, Qs[0] + w * 512);
        gload16(qsrc + 32, Qs[1] + w * 512);
        gload16(ksrc0, Ks[0][0] + w * 512);
        gload16(ksrc0 + 32, Ks[0][1] + w * 512);
        gload16(vsrc0, Vs[0][0] + w * 512);
        gload16(vsrc0 + 32, Vs[0][1] + w * 512);
    }
    __syncthreads();

    // Q fragments -> registers (static indexing; 32 VGPRs)
    short8 qf[2][4];
#pragma unroll
    for (int dsl = 0; dsl < 2; dsl++)
#pragma unroll
        for (int nq = 0; nq < 4; nq++)
            qf[dsl][nq] = *(const short8*)&Qs[dsl][(nq * 16 + col) * 32 + quad * 8];

    floatx4 acc[4];
#pragma unroll
    for (int i = 0; i < 4; i++) acc[i] = (floatx4){0.f, 0.f, 0.f, 0.f};
    float esum[4] = {0.f, 0.f, 0.f, 0.f};

    for (int kc = 0; kc < 16; kc++) {
        int cur = kc & 1;
        // ---- QK: wave w owns chunk-local keys [w*16, +16) ----
        short8 kf0 = *(const short8*)&Ks[cur][0][(w * 16 + col) * 32 + quad * 8];
        short8 kf1 = *(const short8*)&Ks[cur][1][(w * 16 + col) * 32 + quad * 8];
#pragma unroll
        for (int nq = 0; nq < 4; nq++) {
            floatx4 c = {0.f, 0.f, 0.f, 0.f};
            c = __builtin_amdgcn_mfma_f32_16x16x32_bf16(kf0, qf[0][nq], c, 0, 0, 0);
            c = __builtin_amdgcn_mfma_f32_16x16x32_bf16(kf1, qf[1][nq], c, 0, 0, 0);
            float e0 = __expf(c[0] * 0.125f);
            float e1 = __expf(c[1] * 0.125f);
            float e2 = __expf(c[2] * 0.125f);
            float e3 = __expf(c[3] * 0.125f);
            esum[nq] += (e0 + e1) + (e2 + e3);
            union { float f; u32 u; } a0, a1, a2, a3;
            a0.f = e0; a1.f = e1; a2.f = e2; a3.f = e3;
            u32 p0 = (a0.u >> 16) | (a1.u & 0xFFFF0000u);   // bf16 trunc x2
            u32 p1 = (a2.u >> 16) | (a3.u & 0xFFFF0000u);
            u32* sp = (u32*)&S[nq * 16 + col][w * 16 + quad * 4];
            sp[0] = p0; sp[1] = p1;
            u32* gp = (u32*)(Se + splane + (size_t)(q0 + nq * 16 + col) * CS
                             + kc * 64 + w * 16 + quad * 4);
            gp[0] = p0; gp[1] = p1;
        }
        __syncthreads();   // barrier A: S complete

        // prefetch next K/V chunk (overlaps PV below)
        if (kc < 15) {
            int ko = (kc + 1) * 64;
            const u16* ks = ksrc0 + (size_t)ko * 1536;
            gload16(ks, Ks[cur ^ 1][0] + w * 512);
            gload16(ks + 32, Ks[cur ^ 1][1] + w * 512);
            gload16(vsrc0 + ko, Vs[cur ^ 1][0] + w * 512);
            gload16(vsrc0 + ko + 32, Vs[cur ^ 1][1] + w * 512);
        }

        // ---- PV: wave w owns q-subtile [w*16,+16), all 64 d ----
        short8 sf0 = *(const short8*)&S[w * 16 + col][quad * 8];
        short8 sf1 = *(const short8*)&S[w * 16 + col][32 + quad * 8];
#pragma unroll
        for (int nd = 0; nd < 4; nd++) {
            short8 vf0 = *(const short8*)&Vs[cur][0][(nd * 16 + col) * 32 + quad * 8];
            short8 vf1 = *(const short8*)&Vs[cur][1][(nd * 16 + col) * 32 + quad * 8];
            acc[nd] = __builtin_amdgcn_mfma_f32_16x16x32_bf16(sf0, vf0, acc[nd], 0, 0, 0);
            acc[nd] = __builtin_amdgcn_mfma_f32_16x16x32_bf16(sf1, vf1, acc[nd], 0, 0, 0);
        }
        __syncthreads();   // barrier B: S reusable; prefetch drained
    }

    // rowsums
#pragma unroll
    for (int nq = 0; nq < 4; nq++) {
        float v = esum[nq];
        v += __shfl_xor(v, 16, 64);
        v += __shfl_xor(v, 32, 64);
        if (quad == 0) rs[w][nq][col] = v;
    }
    __syncthreads();
    if (t < 64) {
        int nq = t >> 4, c2 = t & 15;
        float L = rs[0][nq][c2] + rs[1][nq][c2] + rs[2][nq][c2] + rs[3][nq][c2];
        Lout[((size_t)bh << 10) + q0 + nq * 16 + c2] = L;
    }

    // ctx: q = q0 + w*16 + quad*4 + r, d = nd*16 + col
    float li[4];
#pragma unroll
    for (int r = 0; r < 4; r++) {
        int cr = quad * 4 + r;
        li[r] = 1.0f / (rs[0][w][cr] + rs[1][w][cr] + rs[2][w][cr] + rs[3][w][cr]);
    }
    u16* cb = ctx + ((size_t)(b * CS) + q0 + w * 16 + quad * 4) * CD + h * CHD + col;
#pragma unroll
    for (int nd = 0; nd < 4; nd++)
#pragma unroll
        for (int r = 0; r < 4; r++)
            cb[(size_t)r * CD + nd * 16] = f2bf(acc[nd][r] * li[r]);
}

// ---------------------------------------------------------------------------
// attn_aw: aw[b,q,k] = (1/8) sum_h S_e[b,h,q,k] / L[b,h,q]. Pure streaming.
// ---------------------------------------------------------------------------
__global__ __launch_bounds__(256, 8) void attn_aw_kernel(
    const u16* __restrict__ Se, const float* __restrict__ Lin,
    float* __restrict__ aw_out, int b0)
{
    int bq = blockIdx.x;               // 2048: 4 b x 512 q-pairs
    int bl = bq >> 9;                  // half-local batch 0..3
    int b = b0 + bl;
    int q = (bq & 511) * 2 + (threadIdx.x >> 7);
    int k0 = (threadIdx.x & 127) * 8;

    float acc[8];
#pragma unroll
    for (int i = 0; i < 8; i++) acc[i] = 0.f;

#pragma unroll
    for (int h = 0; h < CH; h++) {
        float linv = 0.125f / Lin[(((size_t)(b * CH + h)) << 10) + q];
        const u16* sp = Se + ((size_t)(bl * CH + h) * CS + q) * CS + k0;
        ushort8v e = *(const ushort8v*)sp;
#pragma unroll
        for (int i = 0; i < 8; i++) acc[i] += bf2f(e[i]) * linv;
    }
    float* ap = aw_out + ((size_t)(b * CS) + q) * CS + k0;
    *(float4*)ap = make_float4(acc[0], acc[1], acc[2], acc[3]);
    *(float4*)(ap + 4) = make_float4(acc[4], acc[5], acc[6], acc[7]);
}

// ---------------------------------------------------------------------------
extern "C" void kernel_launch(void* const* d_in, const int* in_sizes, int n_in,
                              void* d_out, int out_size, void* d_ws, size_t ws_size,
                              hipStream_t stream)
{
    const float* x    = (const float*)d_in[0];
    const int*   ids  = (const int*)d_in[1];
    const float* emb  = (const float*)d_in[2];
    const float* inw  = (const float*)d_in[3];
    const float* inb  = (const float*)d_in[4];
    const float* ow   = (const float*)d_in[5];
    const float* ob   = (const float*)d_in[6];
    const float* g1   = (const float*)d_in[7];
    const float* be1  = (const float*)d_in[8];
    const float* g2   = (const float*)d_in[9];
    const float* be2  = (const float*)d_in[10];
    const float* w1   = (const float*)d_in[11];
    const float* b1   = (const float*)d_in[12];
    const float* w2   = (const float*)d_in[13];
    const float* b2   = (const float*)d_in[14];

    float* out_x  = (float*)d_out;
    float* out_aw = out_x + (size_t)CB * CS * CD;

    char* p = (char*)d_ws;
    float* xr   = (float*)p; p += (size_t)NROW * CD * 4;
    float* x2   = (float*)p; p += (size_t)NROW * CD * 4;
    u16* xnb    = (u16*)p;   p += (size_t)NROW * CD * 2;
    u16* qkvb   = (u16*)p;   p += (size_t)NROW * 3 * CD * 2;
    u16* ctxb   = (u16*)p;   p += (size_t)NROW * CD * 2;
    u16* hidb   = (u16*)p;   p += (size_t)NROW * CDFF * 2;
    u16* inwb   = (u16*)p;   p += (size_t)3 * CD * CD * 2;   // 4 weight buffers:
    u16* owb    = (u16*)p;   p += (size_t)CD * CD * 2;       //  contiguous (conv4)
    u16* w1b    = (u16*)p;   p += (size_t)CDFF * CD * 2;
    u16* w2b    = (u16*)p;   p += (size_t)CD * CDFF * 2;
    float* Lbuf = (float*)p; p += (size_t)CB * CH * CS * 4;   // rowsums, 256KB
    u16* Se     = (u16*)p;   p += (size_t)(CB / 2) * CH * CS * CS * 2;  // 67MB

    // vt aliases the hidb region (hidb only becomes live at step 6)
    u16* vtb = hidb;   // [b][h][64][CS], 8.4MB <= 33.6MB

    dim3 blk(256);
    // 0) weight conversions (single launch; dst regions contiguous)
    conv4_kernel<<<(3 * CD * CD + CD * CD + 2 * CDFF * CD) / 2048, blk, 0, stream>>>(
        inw, ow, w1, w2, inwb);
    // 1) x+emb, LN1 -> xr fp32, xnb bf16
    ln_kernel<<<NROW, blk, 0, stream>>>(x, ids, emb, g1, be1, xr, xnb);
    // 2) qkv projection (bf16 MFMA, bf16 out)
    gemm_mfma<0, 0, 1><<<dim3(NROW / 128, (3 * CD) / 128), blk, 0, stream>>>(
        xnb, inwb, inb, nullptr, qkvb, NROW, 3 * CD, CD);
    // 3a) V transpose
    vt_kernel<<<dim3(CB * (CS / 64), CH), blk, 0, stream>>>(qkvb, vtb);
    // 3b) fused staged attention (QK+exp+PV) + streaming aw, 2 batch-halves
    for (int half = 0; half < 2; half++) {
        int b0 = half * 4;
        attn_fused_kernel<<<512, blk, 0, stream>>>(qkvb, vtb, Se, Lbuf, ctxb, b0);
        attn_aw_kernel<<<2048, blk, 0, stream>>>(Se, Lbuf, out_aw, b0);
    }
    // 4) out projection + residual -> x2 fp32 (64x128 tiles: 512 blocks)
    gemm_mfma64<0, 1, 0><<<dim3(NROW / 64, CD / 128), blk, 0, stream>>>(
        ctxb, owb, ob, xr, x2, NROW, CD, CD);
    // 5) LN2 -> xnb bf16
    ln_kernel<<<NROW, blk, 0, stream>>>(x2, nullptr, nullptr, g2, be2, nullptr, xnb);
    // 6) FFN up + fast GELU -> hidb bf16
    gemm_mfma<1, 0, 1><<<dim3(NROW / 128, CDFF / 128), blk, 0, stream>>>(
        xnb, w1b, b1, nullptr, hidb, NROW, CDFF, CD);
    // 7) FFN down + bias + residual -> output fp32 (64x128 tiles: 512 blocks)
    gemm_mfma64<0, 1, 0><<<dim3(NROW / 64, CD / 128), blk, 0, stream>>>(
        hidb, w2b, b2, x2, out_x, NROW, CD, CDFF);
}

// Round 9
// 309.120 us; speedup vs baseline: 1.0319x; 1.0319x over previous
//
#include <hip/hip_runtime.h>
#include <math.h>

// Problem constants
constexpr int CB = 8;      // batch
constexpr int CS = 1024;   // seq
constexpr int CD = 512;    // model dim
constexpr int CH = 8;      // heads
constexpr int CHD = 64;    // head dim
constexpr int CDFF = 2048; // ffn dim
constexpr int NROW = CB * CS;

typedef unsigned short u16;
typedef unsigned int u32;
typedef __attribute__((ext_vector_type(8))) short short8;
typedef __attribute__((ext_vector_type(8))) unsigned short ushort8v;
typedef __attribute__((ext_vector_type(4))) float floatx4;

__device__ inline u16 f2bf(float f) {
    union { float f; unsigned u; } v; v.f = f;
    unsigned u = v.u + 0x7FFFu + ((v.u >> 16) & 1u);  // RNE
    return (u16)(u >> 16);
}
__device__ inline float bf2f(u16 h) {
    union { unsigned u; float f; } v; v.u = ((unsigned)h) << 16;
    return v.f;
}

// tanh-form GELU: max abs err vs exact-erf GELU ~3e-4 -> ~1e-4 at output
__device__ inline float gelu_fast(float v) {
    float u = v * (1.0f + 0.044715f * v * v);
    float e = __expf(-1.5957691216057308f * u);
    return v / (1.0f + e);
}

// async global->LDS, 16B per lane; LDS dest is wave-uniform base + lane*16.
__device__ inline void gload16(const u16* g, u16* l) {
    __builtin_amdgcn_global_load_lds(
        (const __attribute__((address_space(1))) u32*)g,
        (__attribute__((address_space(3))) u32*)l, 16, 0, 0);
}

// raw workgroup barrier with compiler memory fences (no vmcnt drain!)
__device__ inline void barrier_raw() {
    asm volatile("" ::: "memory");
    __builtin_amdgcn_s_barrier();
    asm volatile("" ::: "memory");
}

// LDS chunk-swizzle (T2, rule #21): tiles are [rows][32 elems] = 64B rows of
// four 16B chunks. Linear LDS + inverse-swizzled GLOBAL source + swizzled
// read: chunk ^= (row>>1)&3. Staging lane t covers row t>>2, so source chunk
// = (t&3) ^ ((t>>3)&3). Fragment reads at row (16a+col) use chunk
// quad ^ ((col>>1)&3). Result: quarter-wave hits 8 distinct 16B slots 2-way
// (free) instead of 8-way.
#define SRC_CHUNK(t) ((((t) & 3) ^ (((t) >> 3) & 3)) * 8)

// ---------------------------------------------------------------------------
// LayerNorm (+ optional embedding add). One block per row, 256 threads.
// ---------------------------------------------------------------------------
__global__ __launch_bounds__(256) void ln_kernel(
    const float* __restrict__ x, const int* __restrict__ ids,
    const float* __restrict__ emb,
    const float* __restrict__ g, const float* __restrict__ beta,
    float* __restrict__ xr_out, u16* __restrict__ xn_out)
{
    __shared__ float red1[4], red2[4];
    __shared__ float mu_s, ri_s;
    int row = blockIdx.x;
    int tid = threadIdx.x;
    int d0 = tid * 2;
    const float* xrow = x + (size_t)row * CD;
    float2 xv = *(const float2*)(xrow + d0);
    float v0 = xv.x, v1 = xv.y;
    if (emb) {
        int id = ids[row];
        float2 ev = *(const float2*)(emb + (size_t)id * CD + d0);
        v0 += ev.x; v1 += ev.y;
    }
    float s1 = v0 + v1;
    float s2 = v0 * v0 + v1 * v1;
    for (int off = 32; off > 0; off >>= 1) {
        s1 += __shfl_down(s1, off, 64);
        s2 += __shfl_down(s2, off, 64);
    }
    int wave = tid >> 6;
    if ((tid & 63) == 0) { red1[wave] = s1; red2[wave] = s2; }
    __syncthreads();
    if (tid == 0) {
        float t1 = red1[0] + red1[1] + red1[2] + red1[3];
        float t2 = red2[0] + red2[1] + red2[2] + red2[3];
        float mu = t1 / CD;
        float var = t2 / CD - mu * mu;
        mu_s = mu;
        ri_s = rsqrtf(var + 1e-5f);
    }
    __syncthreads();
    float mu = mu_s, ri = ri_s;
    if (xr_out) {
        float2 o; o.x = v0; o.y = v1;
        *(float2*)(xr_out + (size_t)row * CD + d0) = o;
    }
    float2 gv = *(const float2*)(g + d0);
    float2 bv = *(const float2*)(beta + d0);
    float n0 = (v0 - mu) * ri * gv.x + bv.x;
    float n1 = (v1 - mu) * ri * gv.y + bv.y;
    u32 pk = (u32)f2bf(n0) | ((u32)f2bf(n1) << 16);
    *(u32*)(xn_out + (size_t)row * CD + d0) = pk;
}

// ---------------------------------------------------------------------------
// fp32 -> bf16 convert for ALL 4 weight tensors in one launch.
// ---------------------------------------------------------------------------
__global__ __launch_bounds__(256) void conv4_kernel(
    const float* __restrict__ s0, const float* __restrict__ s1,
    const float* __restrict__ s2, const float* __restrict__ s3,
    u16* __restrict__ dst)
{
    size_t i = ((size_t)blockIdx.x * 256 + threadIdx.x) * 8;
    const float* src;
    size_t off;
    if (i < 786432)        { src = s0; off = i; }
    else if (i < 1048576)  { src = s1; off = i - 786432; }
    else if (i < 2097152)  { src = s2; off = i - 1048576; }
    else                   { src = s3; off = i - 2097152; }
    float4 a = *(const float4*)(src + off);
    float4 b = *(const float4*)(src + off + 4);
    ushort8v o;
    o[0] = f2bf(a.x); o[1] = f2bf(a.y); o[2] = f2bf(a.z); o[3] = f2bf(a.w);
    o[4] = f2bf(b.x); o[5] = f2bf(b.y); o[6] = f2bf(b.z); o[7] = f2bf(b.w);
    *(ushort8v*)(dst + i) = o;
}

// ---------------------------------------------------------------------------
// bf16 MFMA GEMM, 128x128 tile. DEPTH-3 counted-vmcnt pipeline (prefetch
// lead = 2 iterations ~ covers HBM latency) + T2 chunk-swizzle (2-way LDS).
// ---------------------------------------------------------------------------
template <int ACT, int RES, int OUTBF>
__global__ __launch_bounds__(256) void gemm_mfma(
    const u16* __restrict__ A, const u16* __restrict__ W,
    const float* __restrict__ bias, const float* __restrict__ res,
    void* __restrict__ Cout, int M, int N, int K)
{
    __shared__ u16 As[3][128 * 32];
    __shared__ u16 Bs[3][128 * 32];
    int t = threadIdx.x;
    int lane = t & 63;
    int w = t >> 6;
    int m0 = blockIdx.x * 128;
    int n0 = blockIdx.y * 128;
    int col = lane & 15;
    int quad = lane >> 4;
    int wm = w & 1, wn = w >> 1;
    int lo = w * 512;                          // wave-local staging dest
    int qs8 = (quad ^ ((col >> 1) & 3)) * 8;   // swizzled read chunk

    const u16* ag = A + (size_t)(m0 + (t >> 2)) * K + SRC_CHUNK(t);
    const u16* ag2 = ag + (size_t)64 * K;
    const u16* bg = W + (size_t)(n0 + (t >> 2)) * K + SRC_CHUNK(t);
    const u16* bg2 = bg + (size_t)64 * K;

    // prologue: stage K-tiles 0,1,2 (12 loads/wave in flight)
#pragma unroll
    for (int i = 0; i < 3; i++) {
        gload16(ag + i * 32, As[i] + lo);
        gload16(ag2 + i * 32, As[i] + 2048 + lo);
        gload16(bg + i * 32, Bs[i] + lo);
        gload16(bg2 + i * 32, Bs[i] + 2048 + lo);
    }

    floatx4 acc[4][4];
#pragma unroll
    for (int i = 0; i < 4; i++)
#pragma unroll
        for (int j = 0; j < 4; j++) acc[i][j] = (floatx4){0.f, 0.f, 0.f, 0.f};

    int nk = K >> 5;
    for (int kt = 0; kt < nk; kt++) {
        int cur = kt % 3;
        // wait for tile kt's 4 loads; up to 8 newer loads stay in flight
        if (kt < nk - 2)       asm volatile("s_waitcnt vmcnt(8)" ::: "memory");
        else if (kt == nk - 2) asm volatile("s_waitcnt vmcnt(4)" ::: "memory");
        else                   asm volatile("s_waitcnt vmcnt(0)" ::: "memory");
        barrier_raw();      // all waves' buf[cur] slices landed
        short8 af[4], bf[4];
#pragma unroll
        for (int mi = 0; mi < 4; mi++)
            af[mi] = *(const short8*)&As[cur][(wm * 64 + mi * 16 + col) * 32 + qs8];
#pragma unroll
        for (int ni = 0; ni < 4; ni++)
            bf[ni] = *(const short8*)&Bs[cur][(wn * 64 + ni * 16 + col) * 32 + qs8];
#pragma unroll
        for (int mi = 0; mi < 4; mi++)
#pragma unroll
            for (int ni = 0; ni < 4; ni++)
                acc[mi][ni] = __builtin_amdgcn_mfma_f32_16x16x32_bf16(
                    af[mi], bf[ni], acc[mi][ni], 0, 0, 0);
        barrier_raw();      // all waves done reading buf[cur]
        if (kt + 3 < nk) {  // stage tile kt+3 into buf[cur] (just released)
            int ko = (kt + 3) * 32;
            gload16(ag + ko, As[cur] + lo);
            gload16(ag2 + ko, As[cur] + 2048 + lo);
            gload16(bg + ko, Bs[cur] + lo);
            gload16(bg2 + ko, Bs[cur] + 2048 + lo);
        }
    }

#pragma unroll
    for (int mi = 0; mi < 4; mi++)
#pragma unroll
        for (int ni = 0; ni < 4; ni++) {
            int c = n0 + wn * 64 + ni * 16 + col;
            float bv = bias[c];
#pragma unroll
            for (int r = 0; r < 4; r++) {
                int m = m0 + wm * 64 + mi * 16 + quad * 4 + r;
                float v = acc[mi][ni][r] + bv;
                if (ACT == 1) v = gelu_fast(v);
                if (RES) v += res[(size_t)m * N + c];
                if (OUTBF) ((u16*)Cout)[(size_t)m * N + c] = f2bf(v);
                else       ((float*)Cout)[(size_t)m * N + c] = v;
            }
        }
}

// ---------------------------------------------------------------------------
// bf16 MFMA GEMM, 64x128 tile. Depth-3 counted vmcnt + chunk-swizzle.
// ---------------------------------------------------------------------------
template <int ACT, int RES, int OUTBF>
__global__ __launch_bounds__(256) void gemm_mfma64(
    const u16* __restrict__ A, const u16* __restrict__ W,
    const float* __restrict__ bias, const float* __restrict__ res,
    void* __restrict__ Cout, int M, int N, int K)
{
    __shared__ u16 As[3][64 * 32];
    __shared__ u16 Bs[3][128 * 32];
    int t = threadIdx.x;
    int lane = t & 63;
    int w = t >> 6;
    int m0 = blockIdx.x * 64;
    int n0 = blockIdx.y * 128;
    int col = lane & 15;
    int quad = lane >> 4;
    int lo = w * 512;
    int qs8 = (quad ^ ((col >> 1) & 3)) * 8;

    const u16* ag = A + (size_t)(m0 + (t >> 2)) * K + SRC_CHUNK(t);
    const u16* bg = W + (size_t)(n0 + (t >> 2)) * K + SRC_CHUNK(t);
    const u16* bg2 = bg + (size_t)64 * K;

    // prologue: stage K-tiles 0,1,2 (9 loads/wave in flight)
#pragma unroll
    for (int i = 0; i < 3; i++) {
        gload16(ag + i * 32, As[i] + lo);
        gload16(bg + i * 32, Bs[i] + lo);
        gload16(bg2 + i * 32, Bs[i] + 2048 + lo);
    }

    floatx4 acc[4][2];
#pragma unroll
    for (int i = 0; i < 4; i++)
#pragma unroll
        for (int j = 0; j < 2; j++) acc[i][j] = (floatx4){0.f, 0.f, 0.f, 0.f};

    int nk = K >> 5;
    for (int kt = 0; kt < nk; kt++) {
        int cur = kt % 3;
        if (kt < nk - 2)       asm volatile("s_waitcnt vmcnt(6)" ::: "memory");
        else if (kt == nk - 2) asm volatile("s_waitcnt vmcnt(3)" ::: "memory");
        else                   asm volatile("s_waitcnt vmcnt(0)" ::: "memory");
        barrier_raw();
        short8 af[4], bf[2];
#pragma unroll
        for (int mi = 0; mi < 4; mi++)
            af[mi] = *(const short8*)&As[cur][(mi * 16 + col) * 32 + qs8];
#pragma unroll
        for (int ni = 0; ni < 2; ni++)
            bf[ni] = *(const short8*)&Bs[cur][(w * 32 + ni * 16 + col) * 32 + qs8];
#pragma unroll
        for (int mi = 0; mi < 4; mi++)
#pragma unroll
            for (int ni = 0; ni < 2; ni++)
                acc[mi][ni] = __builtin_amdgcn_mfma_f32_16x16x32_bf16(
                    af[mi], bf[ni], acc[mi][ni], 0, 0, 0);
        barrier_raw();
        if (kt + 3 < nk) {
            int ko = (kt + 3) * 32;
            gload16(ag + ko, As[cur] + lo);
            gload16(bg + ko, Bs[cur] + lo);
            gload16(bg2 + ko, Bs[cur] + 2048 + lo);
        }
    }

#pragma unroll
    for (int mi = 0; mi < 4; mi++)
#pragma unroll
        for (int ni = 0; ni < 2; ni++) {
            int c = n0 + w * 32 + ni * 16 + col;
            float bv = bias[c];
#pragma unroll
            for (int r = 0; r < 4; r++) {
                int m = m0 + mi * 16 + quad * 4 + r;
                float v = acc[mi][ni][r] + bv;
                if (ACT == 1) v = gelu_fast(v);
                if (RES) v += res[(size_t)m * N + c];
                if (OUTBF) ((u16*)Cout)[(size_t)m * N + c] = f2bf(v);
                else       ((float*)Cout)[(size_t)m * N + c] = v;
            }
        }
}

// ---------------------------------------------------------------------------
// V transpose: qkv cols 1024.. -> vt [b][h][d=64][S] (rows of S, 2KB)
// ---------------------------------------------------------------------------
__global__ __launch_bounds__(256) void vt_kernel(
    const u16* __restrict__ qkvb, u16* __restrict__ vt)
{
    __shared__ u16 tile[64][72];
    int b = blockIdx.x >> 4;
    int s0 = (blockIdx.x & 15) * 64;
    int h = blockIdx.y;
    int t = threadIdx.x;
    int r = t >> 2;
    int c0 = (t & 3) * 16;
    const u16* src = qkvb + (size_t)(b * CS + s0 + r) * 1536 + 2 * CD + h * CHD + c0;
    *(ushort8v*)&tile[r][c0] = *(const ushort8v*)src;
    *(ushort8v*)&tile[r][c0 + 8] = *(const ushort8v*)(src + 8);
    __syncthreads();
    u16* dst = vt + (((size_t)b * CH + h) * CHD + r) * CS + s0 + c0;
    ushort8v lo, hi;
#pragma unroll
    for (int j = 0; j < 8; j++) { lo[j] = tile[c0 + j][r]; hi[j] = tile[c0 + 8 + j][r]; }
    *(ushort8v*)dst = lo;
    *(ushort8v*)(dst + 8) = hi;
}

// ---------------------------------------------------------------------------
// attn_fused: QK + exp + PV in one staged kernel. Block = (b,h,64-q-tile),
// 512/half, 4 waves. Q/K/V tiles now chunk-swizzled (same T2 scheme).
// ---------------------------------------------------------------------------
__global__ __launch_bounds__(256, 2) void attn_fused_kernel(
    const u16* __restrict__ qkvb, const u16* __restrict__ vt,
    u16* __restrict__ Se, float* __restrict__ Lout,
    u16* __restrict__ ctx, int b0)
{
    __shared__ u16 Qs[2][64 * 32];      // [dsl][q][d-slice]        8 KB
    __shared__ u16 Ks[2][2][64 * 32];   // [buf][dsl][k][d-slice]  16 KB
    __shared__ u16 Vs[2][2][64 * 32];   // [buf][ksl][d][k-slice]  16 KB
    __shared__ u16 S[64][72];           // q x chunk-k (16B rows)  9.2 KB
    __shared__ float rs[4][4][16];

    int t = threadIdx.x;
    int lane = t & 63;
    int w = t >> 6;
    int col = lane & 15;
    int quad = lane >> 4;
    int qs8 = (quad ^ ((col >> 1) & 3)) * 8;   // swizzled read chunk
    int bid = blockIdx.x;           // 512
    int xcd = bid & 7;
    int j = bid >> 3;               // 0..63
    int bhl = xcd * 4 + (j >> 4);   // 0..31
    int qt = j & 15;
    int lb = bhl >> 3, h = bhl & 7;
    int b = b0 + lb;
    int q0 = qt * 64;
    int bh = b * CH + h;
    size_t splane = (size_t)(lb * CH + h) * CS * CS;

    int srow = t >> 2;              // staged row 0..63
    int scol = SRC_CHUNK(t);        // pre-swizzled source chunk

    const u16* ksrc0 = qkvb + (size_t)(b * CS + srow) * 1536 + CD + h * CHD + scol;
    const u16* vsrc0 = vt + ((size_t)bh * CHD + srow) * CS + scol;

    // prologue: Q (both d-slices) + K/V chunk 0
    {
        const u16* qsrc = qkvb + (size_t)(b * CS + q0 + srow) * 1536 + h * CHD + scol;
        gload16(qsrc, Qs[0] + w * 512);
        gload16(qsrc + 32, Qs[1] + w * 512);
        gload16(ksrc0, Ks[0][0] + w * 512);
        gload16(ksrc0 + 32, Ks[0][1] + w * 512);
        gload16(vsrc0, Vs[0][0] + w * 512);
        gload16(vsrc0 + 32, Vs[0][1] + w * 512);
    }
    __syncthreads();

    // Q fragments -> registers (static indexing; 32 VGPRs)
    short8 qf[2][4];
#pragma unroll
    for (int dsl = 0; dsl < 2; dsl++)
#pragma unroll
        for (int nq = 0; nq < 4; nq++)
            qf[dsl][nq] = *(const short8*)&Qs[dsl][(nq * 16 + col) * 32 + qs8];

    floatx4 acc[4];
#pragma unroll
    for (int i = 0; i < 4; i++) acc[i] = (floatx4){0.f, 0.f, 0.f, 0.f};
    float esum[4] = {0.f, 0.f, 0.f, 0.f};

    for (int kc = 0; kc < 16; kc++) {
        int cur = kc & 1;
        // ---- QK: wave w owns chunk-local keys [w*16, +16) ----
        short8 kf0 = *(const short8*)&Ks[cur][0][(w * 16 + col) * 32 + qs8];
        short8 kf1 = *(const short8*)&Ks[cur][1][(w * 16 + col) * 32 + qs8];
#pragma unroll
        for (int nq = 0; nq < 4; nq++) {
            floatx4 c = {0.f, 0.f, 0.f, 0.f};
            c = __builtin_amdgcn_mfma_f32_16x16x32_bf16(kf0, qf[0][nq], c, 0, 0, 0);
            c = __builtin_amdgcn_mfma_f32_16x16x32_bf16(kf1, qf[1][nq], c, 0, 0, 0);
            float e0 = __expf(c[0] * 0.125f);
            float e1 = __expf(c[1] * 0.125f);
            float e2 = __expf(c[2] * 0.125f);
            float e3 = __expf(c[3] * 0.125f);
            esum[nq] += (e0 + e1) + (e2 + e3);
            union { float f; u32 u; } a0, a1, a2, a3;
            a0.f = e0; a1.f = e1; a2.f = e2; a3.f = e3;
            u32 p0 = (a0.u >> 16) | (a1.u & 0xFFFF0000u);   // bf16 trunc x2
            u32 p1 = (a2.u >> 16) | (a3.u & 0xFFFF0000u);
            u32* sp = (u32*)&S[nq * 16 + col][w * 16 + quad * 4];
            sp[0] = p0; sp[1] = p1;
            u32* gp = (u32*)(Se + splane + (size_t)(q0 + nq * 16 + col) * CS
                             + kc * 64 + w * 16 + quad * 4);
            gp[0] = p0; gp[1] = p1;
        }
        __syncthreads();   // barrier A: S complete

        // prefetch next K/V chunk (overlaps PV below)
        if (kc < 15) {
            int ko = (kc + 1) * 64;
            const u16* ks = ksrc0 + (size_t)ko * 1536;
            gload16(ks, Ks[cur ^ 1][0] + w * 512);
            gload16(ks + 32, Ks[cur ^ 1][1] + w * 512);
            gload16(vsrc0 + ko, Vs[cur ^ 1][0] + w * 512);
            gload16(vsrc0 + ko + 32, Vs[cur ^ 1][1] + w * 512);
        }

        // ---- PV: wave w owns q-subtile [w*16,+16), all 64 d ----
        short8 sf0 = *(const short8*)&S[w * 16 + col][quad * 8];
        short8 sf1 = *(const short8*)&S[w * 16 + col][32 + quad * 8];
#pragma unroll
        for (int nd = 0; nd < 4; nd++) {
            short8 vf0 = *(const short8*)&Vs[cur][0][(nd * 16 + col) * 32 + qs8];
            short8 vf1 = *(const short8*)&Vs[cur][1][(nd * 16 + col) * 32 + qs8];
            acc[nd] = __builtin_amdgcn_mfma_f32_16x16x32_bf16(sf0, vf0, acc[nd], 0, 0, 0);
            acc[nd] = __builtin_amdgcn_mfma_f32_16x16x32_bf16(sf1, vf1, acc[nd], 0, 0, 0);
        }
        __syncthreads();   // barrier B: S reusable; prefetch drained
    }

    // rowsums
#pragma unroll
    for (int nq = 0; nq < 4; nq++) {
        float v = esum[nq];
        v += __shfl_xor(v, 16, 64);
        v += __shfl_xor(v, 32, 64);
        if (quad == 0) rs[w][nq][col] = v;
    }
    __syncthreads();
    if (t < 64) {
        int nq = t >> 4, c2 = t & 15;
        float L = rs[0][nq][c2] + rs[1][nq][c2] + rs[2][nq][c2] + rs[3][nq][c2];
        Lout[((size_t)bh << 10) + q0 + nq * 16 + c2] = L;
    }

    // ctx: q = q0 + w*16 + quad*4 + r, d = nd*16 + col
    float li[4];
#pragma unroll
    for (int r = 0; r < 4; r++) {
        int cr = quad * 4 + r;
        li[r] = 1.0f / (rs[0][w][cr] + rs[1][w][cr] + rs[2][w][cr] + rs[3][w][cr]);
    }
    u16* cb = ctx + ((size_t)(b * CS) + q0 + w * 16 + quad * 4) * CD + h * CHD + col;
#pragma unroll
    for (int nd = 0; nd < 4; nd++)
#pragma unroll
        for (int r = 0; r < 4; r++)
            cb[(size_t)r * CD + nd * 16] = f2bf(acc[nd][r] * li[r]);
}

// ---------------------------------------------------------------------------
// attn_aw: aw[b,q,k] = (1/8) sum_h S_e[b,h,q,k] / L[b,h,q]. Pure streaming.
// ---------------------------------------------------------------------------
__global__ __launch_bounds__(256, 8) void attn_aw_kernel(
    const u16* __restrict__ Se, const float* __restrict__ Lin,
    float* __restrict__ aw_out, int b0)
{
    int bq = blockIdx.x;               // 2048: 4 b x 512 q-pairs
    int bl = bq >> 9;                  // half-local batch 0..3
    int b = b0 + bl;
    int q = (bq & 511) * 2 + (threadIdx.x >> 7);
    int k0 = (threadIdx.x & 127) * 8;

    float acc[8];
#pragma unroll
    for (int i = 0; i < 8; i++) acc[i] = 0.f;

#pragma unroll
    for (int h = 0; h < CH; h++) {
        float linv = 0.125f / Lin[(((size_t)(b * CH + h)) << 10) + q];
        const u16* sp = Se + ((size_t)(bl * CH + h) * CS + q) * CS + k0;
        ushort8v e = *(const ushort8v*)sp;
#pragma unroll
        for (int i = 0; i < 8; i++) acc[i] += bf2f(e[i]) * linv;
    }
    float* ap = aw_out + ((size_t)(b * CS) + q) * CS + k0;
    *(float4*)ap = make_float4(acc[0], acc[1], acc[2], acc[3]);
    *(float4*)(ap + 4) = make_float4(acc[4], acc[5], acc[6], acc[7]);
}

// ---------------------------------------------------------------------------
extern "C" void kernel_launch(void* const* d_in, const int* in_sizes, int n_in,
                              void* d_out, int out_size, void* d_ws, size_t ws_size,
                              hipStream_t stream)
{
    const float* x    = (const float*)d_in[0];
    const int*   ids  = (const int*)d_in[1];
    const float* emb  = (const float*)d_in[2];
    const float* inw  = (const float*)d_in[3];
    const float* inb  = (const float*)d_in[4];
    const float* ow   = (const float*)d_in[5];
    const float* ob   = (const float*)d_in[6];
    const float* g1   = (const float*)d_in[7];
    const float* be1  = (const float*)d_in[8];
    const float* g2   = (const float*)d_in[9];
    const float* be2  = (const float*)d_in[10];
    const float* w1   = (const float*)d_in[11];
    const float* b1   = (const float*)d_in[12];
    const float* w2   = (const float*)d_in[13];
    const float* b2   = (const float*)d_in[14];

    float* out_x  = (float*)d_out;
    float* out_aw = out_x + (size_t)CB * CS * CD;

    char* p = (char*)d_ws;
    float* xr   = (float*)p; p += (size_t)NROW * CD * 4;
    float* x2   = (float*)p; p += (size_t)NROW * CD * 4;
    u16* xnb    = (u16*)p;   p += (size_t)NROW * CD * 2;
    u16* qkvb   = (u16*)p;   p += (size_t)NROW * 3 * CD * 2;
    u16* ctxb   = (u16*)p;   p += (size_t)NROW * CD * 2;
    u16* hidb   = (u16*)p;   p += (size_t)NROW * CDFF * 2;
    u16* inwb   = (u16*)p;   p += (size_t)3 * CD * CD * 2;   // 4 weight buffers:
    u16* owb    = (u16*)p;   p += (size_t)CD * CD * 2;       //  contiguous (conv4)
    u16* w1b    = (u16*)p;   p += (size_t)CDFF * CD * 2;
    u16* w2b    = (u16*)p;   p += (size_t)CD * CDFF * 2;
    float* Lbuf = (float*)p; p += (size_t)CB * CH * CS * 4;   // rowsums, 256KB
    u16* Se     = (u16*)p;   p += (size_t)(CB / 2) * CH * CS * CS * 2;  // 67MB

    // vt aliases the hidb region (hidb only becomes live at step 6)
    u16* vtb = hidb;   // [b][h][64][CS], 8.4MB <= 33.6MB

    dim3 blk(256);
    // 0) weight conversions (single launch; dst regions contiguous)
    conv4_kernel<<<(3 * CD * CD + CD * CD + 2 * CDFF * CD) / 2048, blk, 0, stream>>>(
        inw, ow, w1, w2, inwb);
    // 1) x+emb, LN1 -> xr fp32, xnb bf16
    ln_kernel<<<NROW, blk, 0, stream>>>(x, ids, emb, g1, be1, xr, xnb);
    // 2) qkv projection (bf16 MFMA, bf16 out)
    gemm_mfma<0, 0, 1><<<dim3(NROW / 128, (3 * CD) / 128), blk, 0, stream>>>(
        xnb, inwb, inb, nullptr, qkvb, NROW, 3 * CD, CD);
    // 3a) V transpose
    vt_kernel<<<dim3(CB * (CS / 64), CH), blk, 0, stream>>>(qkvb, vtb);
    // 3b) fused staged attention (QK+exp+PV) + streaming aw, 2 batch-halves
    for (int half = 0; half < 2; half++) {
        int b0 = half * 4;
        attn_fused_kernel<<<512, blk, 0, stream>>>(qkvb, vtb, Se, Lbuf, ctxb, b0);
        attn_aw_kernel<<<2048, blk, 0, stream>>>(Se, Lbuf, out_aw, b0);
    }
    // 4) out projection + residual -> x2 fp32 (64x128 tiles: 512 blocks)
    gemm_mfma64<0, 1, 0><<<dim3(NROW / 64, CD / 128), blk, 0, stream>>>(
        ctxb, owb, ob, xr, x2, NROW, CD, CD);
    // 5) LN2 -> xnb bf16
    ln_kernel<<<NROW, blk, 0, stream>>>(x2, nullptr, nullptr, g2, be2, nullptr, xnb);
    // 6) FFN up + fast GELU -> hidb bf16
    gemm_mfma<1, 0, 1><<<dim3(NROW / 128, CDFF / 128), blk, 0, stream>>>(
        xnb, w1b, b1, nullptr, hidb, NROW, CDFF, CD);
    // 7) FFN down + bias + residual -> output fp32 (64x128 tiles: 512 blocks)
    gemm_mfma64<0, 1, 0><<<dim3(NROW / 64, CD / 128), blk, 0, stream>>>(
        hidb, w2b, b2, x2, out_x, NROW, CD, CDFF);
}

// Round 10
// 306.352 us; speedup vs baseline: 1.0412x; 1.0090x over previous
//
#include <hip/hip_runtime.h>
#include <math.h>

// Problem constants
constexpr int CB = 8;      // batch
constexpr int CS = 1024;   // seq
constexpr int CD = 512;    // model dim
constexpr int CH = 8;      // heads
constexpr int CHD = 64;    // head dim
constexpr int CDFF = 2048; // ffn dim
constexpr int NROW = CB * CS;

typedef unsigned short u16;
typedef unsigned int u32;
typedef __attribute__((ext_vector_type(8))) short short8;
typedef __attribute__((ext_vector_type(8))) unsigned short ushort8v;
typedef __attribute__((ext_vector_type(4))) float floatx4;

__device__ inline u16 f2bf(float f) {
    union { float f; unsigned u; } v; v.f = f;
    unsigned u = v.u + 0x7FFFu + ((v.u >> 16) & 1u);  // RNE
    return (u16)(u >> 16);
}
__device__ inline float bf2f(u16 h) {
    union { unsigned u; float f; } v; v.u = ((unsigned)h) << 16;
    return v.f;
}

// tanh-form GELU: max abs err vs exact-erf GELU ~3e-4 -> ~1e-4 at output
__device__ inline float gelu_fast(float v) {
    float u = v * (1.0f + 0.044715f * v * v);
    float e = __expf(-1.5957691216057308f * u);
    return v / (1.0f + e);
}

// async global->LDS, 16B per lane; LDS dest is wave-uniform base + lane*16.
__device__ inline void gload16(const u16* g, u16* l) {
    __builtin_amdgcn_global_load_lds(
        (const __attribute__((address_space(1))) u32*)g,
        (__attribute__((address_space(3))) u32*)l, 16, 0, 0);
}

// raw workgroup barrier with compiler memory fences (no vmcnt drain!)
__device__ inline void barrier_raw() {
    asm volatile("" ::: "memory");
    __builtin_amdgcn_s_barrier();
    asm volatile("" ::: "memory");
}

// LDS chunk-swizzle (T2, rule #21): tiles are [rows][32 elems] = 64B rows of
// four 16B chunks. Linear LDS + inverse-swizzled GLOBAL source + swizzled
// read: chunk ^= (row>>1)&3. Staging lane t covers row t>>2, so source chunk
// = (t&3) ^ ((t>>3)&3). Fragment reads at row (16a+col) use chunk
// quad ^ ((col>>1)&3). Quarter-wave -> 8 distinct 16B slots 2-way (free).
// VERIFIED R9: SQ_LDS_BANK_CONFLICT 3.1M -> 0.
#define SRC_CHUNK(t) ((((t) & 3) ^ (((t) >> 3) & 3)) * 8)

// ---------------------------------------------------------------------------
// LayerNorm (+ optional embedding add). One block per row, 256 threads.
// ---------------------------------------------------------------------------
__global__ __launch_bounds__(256) void ln_kernel(
    const float* __restrict__ x, const int* __restrict__ ids,
    const float* __restrict__ emb,
    const float* __restrict__ g, const float* __restrict__ beta,
    float* __restrict__ xr_out, u16* __restrict__ xn_out)
{
    __shared__ float red1[4], red2[4];
    __shared__ float mu_s, ri_s;
    int row = blockIdx.x;
    int tid = threadIdx.x;
    int d0 = tid * 2;
    const float* xrow = x + (size_t)row * CD;
    float2 xv = *(const float2*)(xrow + d0);
    float v0 = xv.x, v1 = xv.y;
    if (emb) {
        int id = ids[row];
        float2 ev = *(const float2*)(emb + (size_t)id * CD + d0);
        v0 += ev.x; v1 += ev.y;
    }
    float s1 = v0 + v1;
    float s2 = v0 * v0 + v1 * v1;
    for (int off = 32; off > 0; off >>= 1) {
        s1 += __shfl_down(s1, off, 64);
        s2 += __shfl_down(s2, off, 64);
    }
    int wave = tid >> 6;
    if ((tid & 63) == 0) { red1[wave] = s1; red2[wave] = s2; }
    __syncthreads();
    if (tid == 0) {
        float t1 = red1[0] + red1[1] + red1[2] + red1[3];
        float t2 = red2[0] + red2[1] + red2[2] + red2[3];
        float mu = t1 / CD;
        float var = t2 / CD - mu * mu;
        mu_s = mu;
        ri_s = rsqrtf(var + 1e-5f);
    }
    __syncthreads();
    float mu = mu_s, ri = ri_s;
    if (xr_out) {
        float2 o; o.x = v0; o.y = v1;
        *(float2*)(xr_out + (size_t)row * CD + d0) = o;
    }
    float2 gv = *(const float2*)(g + d0);
    float2 bv = *(const float2*)(beta + d0);
    float n0 = (v0 - mu) * ri * gv.x + bv.x;
    float n1 = (v1 - mu) * ri * gv.y + bv.y;
    u32 pk = (u32)f2bf(n0) | ((u32)f2bf(n1) << 16);
    *(u32*)(xn_out + (size_t)row * CD + d0) = pk;
}

// ---------------------------------------------------------------------------
// fp32 -> bf16 convert for ALL 4 weight tensors in one launch.
// ---------------------------------------------------------------------------
__global__ __launch_bounds__(256) void conv4_kernel(
    const float* __restrict__ s0, const float* __restrict__ s1,
    const float* __restrict__ s2, const float* __restrict__ s3,
    u16* __restrict__ dst)
{
    size_t i = ((size_t)blockIdx.x * 256 + threadIdx.x) * 8;
    const float* src;
    size_t off;
    if (i < 786432)        { src = s0; off = i; }
    else if (i < 1048576)  { src = s1; off = i - 786432; }
    else if (i < 2097152)  { src = s2; off = i - 1048576; }
    else                   { src = s3; off = i - 2097152; }
    float4 a = *(const float4*)(src + off);
    float4 b = *(const float4*)(src + off + 4);
    ushort8v o;
    o[0] = f2bf(a.x); o[1] = f2bf(a.y); o[2] = f2bf(a.z); o[3] = f2bf(a.w);
    o[4] = f2bf(b.x); o[5] = f2bf(b.y); o[6] = f2bf(b.z); o[7] = f2bf(b.w);
    *(ushort8v*)(dst + i) = o;
}

// ---------------------------------------------------------------------------
// bf16 MFMA GEMM, 128x128 tile. DEPTH-2 counted-vmcnt + T2 chunk-swizzle.
// (Depth-3 regressed: 48KB LDS -> 3 blk/CU < grid's 4/CU need -> straggler
// wave. 32KB -> 5 blk/CU, full co-residency for 768/1024-block grids.)
// ---------------------------------------------------------------------------
template <int ACT, int RES, int OUTBF>
__global__ __launch_bounds__(256) void gemm_mfma(
    const u16* __restrict__ A, const u16* __restrict__ W,
    const float* __restrict__ bias, const float* __restrict__ res,
    void* __restrict__ Cout, int M, int N, int K)
{
    __shared__ u16 As[2][128 * 32];
    __shared__ u16 Bs[2][128 * 32];
    int t = threadIdx.x;
    int lane = t & 63;
    int w = t >> 6;
    int m0 = blockIdx.x * 128;
    int n0 = blockIdx.y * 128;
    int col = lane & 15;
    int quad = lane >> 4;
    int wm = w & 1, wn = w >> 1;
    int lo = w * 512;                          // wave-local staging dest
    int qs8 = (quad ^ ((col >> 1) & 3)) * 8;   // swizzled read chunk

    const u16* ag = A + (size_t)(m0 + (t >> 2)) * K + SRC_CHUNK(t);
    const u16* ag2 = ag + (size_t)64 * K;
    const u16* bg = W + (size_t)(n0 + (t >> 2)) * K + SRC_CHUNK(t);
    const u16* bg2 = bg + (size_t)64 * K;

    // prologue: stage K-tiles 0 and 1 (8 loads/wave in flight)
#pragma unroll
    for (int i = 0; i < 2; i++) {
        gload16(ag + i * 32, As[i] + lo);
        gload16(ag2 + i * 32, As[i] + 2048 + lo);
        gload16(bg + i * 32, Bs[i] + lo);
        gload16(bg2 + i * 32, Bs[i] + 2048 + lo);
    }

    floatx4 acc[4][4];
#pragma unroll
    for (int i = 0; i < 4; i++)
#pragma unroll
        for (int j = 0; j < 4; j++) acc[i][j] = (floatx4){0.f, 0.f, 0.f, 0.f};

    int nk = K >> 5;
    for (int kt = 0; kt < nk; kt++) {
        int cur = kt & 1;
        if (kt == nk - 1) asm volatile("s_waitcnt vmcnt(0)" ::: "memory");
        else              asm volatile("s_waitcnt vmcnt(4)" ::: "memory");
        barrier_raw();      // all waves' buf[cur] slices landed
        short8 af[4], bf[4];
#pragma unroll
        for (int mi = 0; mi < 4; mi++)
            af[mi] = *(const short8*)&As[cur][(wm * 64 + mi * 16 + col) * 32 + qs8];
#pragma unroll
        for (int ni = 0; ni < 4; ni++)
            bf[ni] = *(const short8*)&Bs[cur][(wn * 64 + ni * 16 + col) * 32 + qs8];
#pragma unroll
        for (int mi = 0; mi < 4; mi++)
#pragma unroll
            for (int ni = 0; ni < 4; ni++)
                acc[mi][ni] = __builtin_amdgcn_mfma_f32_16x16x32_bf16(
                    af[mi], bf[ni], acc[mi][ni], 0, 0, 0);
        barrier_raw();      // all waves done reading buf[cur]
        if (kt + 2 < nk) {  // stage tile kt+2 into buf[cur] (just released)
            int ko = (kt + 2) * 32;
            gload16(ag + ko, As[cur] + lo);
            gload16(ag2 + ko, As[cur] + 2048 + lo);
            gload16(bg + ko, Bs[cur] + lo);
            gload16(bg2 + ko, Bs[cur] + 2048 + lo);
        }
    }

#pragma unroll
    for (int mi = 0; mi < 4; mi++)
#pragma unroll
        for (int ni = 0; ni < 4; ni++) {
            int c = n0 + wn * 64 + ni * 16 + col;
            float bv = bias[c];
#pragma unroll
            for (int r = 0; r < 4; r++) {
                int m = m0 + wm * 64 + mi * 16 + quad * 4 + r;
                float v = acc[mi][ni][r] + bv;
                if (ACT == 1) v = gelu_fast(v);
                if (RES) v += res[(size_t)m * N + c];
                if (OUTBF) ((u16*)Cout)[(size_t)m * N + c] = f2bf(v);
                else       ((float*)Cout)[(size_t)m * N + c] = v;
            }
        }
}

// ---------------------------------------------------------------------------
// bf16 MFMA GEMM, 64x128 tile. Depth-3 counted vmcnt + chunk-swizzle
// (36KB LDS, grid 512 = 2/CU — capacity not binding; kept from R9, improved).
// ---------------------------------------------------------------------------
template <int ACT, int RES, int OUTBF>
__global__ __launch_bounds__(256) void gemm_mfma64(
    const u16* __restrict__ A, const u16* __restrict__ W,
    const float* __restrict__ bias, const float* __restrict__ res,
    void* __restrict__ Cout, int M, int N, int K)
{
    __shared__ u16 As[3][64 * 32];
    __shared__ u16 Bs[3][128 * 32];
    int t = threadIdx.x;
    int lane = t & 63;
    int w = t >> 6;
    int m0 = blockIdx.x * 64;
    int n0 = blockIdx.y * 128;
    int col = lane & 15;
    int quad = lane >> 4;
    int lo = w * 512;
    int qs8 = (quad ^ ((col >> 1) & 3)) * 8;

    const u16* ag = A + (size_t)(m0 + (t >> 2)) * K + SRC_CHUNK(t);
    const u16* bg = W + (size_t)(n0 + (t >> 2)) * K + SRC_CHUNK(t);
    const u16* bg2 = bg + (size_t)64 * K;

    // prologue: stage K-tiles 0,1,2 (9 loads/wave in flight)
#pragma unroll
    for (int i = 0; i < 3; i++) {
        gload16(ag + i * 32, As[i] + lo);
        gload16(bg + i * 32, Bs[i] + lo);
        gload16(bg2 + i * 32, Bs[i] + 2048 + lo);
    }

    floatx4 acc[4][2];
#pragma unroll
    for (int i = 0; i < 4; i++)
#pragma unroll
        for (int j = 0; j < 2; j++) acc[i][j] = (floatx4){0.f, 0.f, 0.f, 0.f};

    int nk = K >> 5;
    for (int kt = 0; kt < nk; kt++) {
        int cur = kt % 3;
        if (kt < nk - 2)       asm volatile("s_waitcnt vmcnt(6)" ::: "memory");
        else if (kt == nk - 2) asm volatile("s_waitcnt vmcnt(3)" ::: "memory");
        else                   asm volatile("s_waitcnt vmcnt(0)" ::: "memory");
        barrier_raw();
        short8 af[4], bf[2];
#pragma unroll
        for (int mi = 0; mi < 4; mi++)
            af[mi] = *(const short8*)&As[cur][(mi * 16 + col) * 32 + qs8];
#pragma unroll
        for (int ni = 0; ni < 2; ni++)
            bf[ni] = *(const short8*)&Bs[cur][(w * 32 + ni * 16 + col) * 32 + qs8];
#pragma unroll
        for (int mi = 0; mi < 4; mi++)
#pragma unroll
            for (int ni = 0; ni < 2; ni++)
                acc[mi][ni] = __builtin_amdgcn_mfma_f32_16x16x32_bf16(
                    af[mi], bf[ni], acc[mi][ni], 0, 0, 0);
        barrier_raw();
        if (kt + 3 < nk) {
            int ko = (kt + 3) * 32;
            gload16(ag + ko, As[cur] + lo);
            gload16(bg + ko, Bs[cur] + lo);
            gload16(bg2 + ko, Bs[cur] + 2048 + lo);
        }
    }

#pragma unroll
    for (int mi = 0; mi < 4; mi++)
#pragma unroll
        for (int ni = 0; ni < 2; ni++) {
            int c = n0 + w * 32 + ni * 16 + col;
            float bv = bias[c];
#pragma unroll
            for (int r = 0; r < 4; r++) {
                int m = m0 + mi * 16 + quad * 4 + r;
                float v = acc[mi][ni][r] + bv;
                if (ACT == 1) v = gelu_fast(v);
                if (RES) v += res[(size_t)m * N + c];
                if (OUTBF) ((u16*)Cout)[(size_t)m * N + c] = f2bf(v);
                else       ((float*)Cout)[(size_t)m * N + c] = v;
            }
        }
}

// ---------------------------------------------------------------------------
// V transpose: qkv cols 1024.. -> vt [b][h][d=64][S] (rows of S, 2KB)
// ---------------------------------------------------------------------------
__global__ __launch_bounds__(256) void vt_kernel(
    const u16* __restrict__ qkvb, u16* __restrict__ vt)
{
    __shared__ u16 tile[64][72];
    int b = blockIdx.x >> 4;
    int s0 = (blockIdx.x & 15) * 64;
    int h = blockIdx.y;
    int t = threadIdx.x;
    int r = t >> 2;
    int c0 = (t & 3) * 16;
    const u16* src = qkvb + (size_t)(b * CS + s0 + r) * 1536 + 2 * CD + h * CHD + c0;
    *(ushort8v*)&tile[r][c0] = *(const ushort8v*)src;
    *(ushort8v*)&tile[r][c0 + 8] = *(const ushort8v*)(src + 8);
    __syncthreads();
    u16* dst = vt + (((size_t)b * CH + h) * CHD + r) * CS + s0 + c0;
    ushort8v lo, hi;
#pragma unroll
    for (int j = 0; j < 8; j++) { lo[j] = tile[c0 + j][r]; hi[j] = tile[c0 + 8 + j][r]; }
    *(ushort8v*)dst = lo;
    *(ushort8v*)(dst + 8) = hi;
}

// ---------------------------------------------------------------------------
// attn_fused: QK + exp + PV in one staged kernel. Block = (b,h,64-q-tile),
// 512/half, 4 waves. Se is now written COALESCED from LDS S after barrier A
// (2x16B per thread, 128B per 4-lane group) instead of per-lane scattered
// 4B pieces in the QK loop (was ~16x L2 write-port amplification).
// ---------------------------------------------------------------------------
__global__ __launch_bounds__(256, 2) void attn_fused_kernel(
    const u16* __restrict__ qkvb, const u16* __restrict__ vt,
    u16* __restrict__ Se, float* __restrict__ Lout,
    u16* __restrict__ ctx, int b0)
{
    __shared__ u16 Qs[2][64 * 32];      // [dsl][q][d-slice]        8 KB
    __shared__ u16 Ks[2][2][64 * 32];   // [buf][dsl][k][d-slice]  16 KB
    __shared__ u16 Vs[2][2][64 * 32];   // [buf][ksl][d][k-slice]  16 KB
    __shared__ u16 S[64][72];           // q x chunk-k (16B rows)  9.2 KB
    __shared__ float rs[4][4][16];

    int t = threadIdx.x;
    int lane = t & 63;
    int w = t >> 6;
    int col = lane & 15;
    int quad = lane >> 4;
    int qs8 = (quad ^ ((col >> 1) & 3)) * 8;   // swizzled read chunk
    int bid = blockIdx.x;           // 512
    int xcd = bid & 7;
    int j = bid >> 3;               // 0..63
    int bhl = xcd * 4 + (j >> 4);   // 0..31
    int qt = j & 15;
    int lb = bhl >> 3, h = bhl & 7;
    int b = b0 + lb;
    int q0 = qt * 64;
    int bh = b * CH + h;
    size_t splane = (size_t)(lb * CH + h) * CS * CS;

    int srow = t >> 2;              // staged row 0..63
    int scol = SRC_CHUNK(t);        // pre-swizzled source chunk

    const u16* ksrc0 = qkvb + (size_t)(b * CS + srow) * 1536 + CD + h * CHD + scol;
    const u16* vsrc0 = vt + ((size_t)bh * CHD + srow) * CS + scol;

    // prologue: Q (both d-slices) + K/V chunk 0
    {
        const u16* qsrc = qkvb + (size_t)(b * CS + q0 + srow) * 1536 + h * CHD + scol;
        gload16(qsrc, Qs[0] + w * 512);
        gload16(qsrc + 32, Qs[1] + w * 512);
        gload16(ksrc0, Ks[0][0] + w * 512);
        gload16(ksrc0 + 32, Ks[0][1] + w * 512);
        gload16(vsrc0, Vs[0][0] + w * 512);
        gload16(vsrc0 + 32, Vs[0][1] + w * 512);
    }
    __syncthreads();

    // Q fragments -> registers (static indexing; 32 VGPRs)
    short8 qf[2][4];
#pragma unroll
    for (int dsl = 0; dsl < 2; dsl++)
#pragma unroll
        for (int nq = 0; nq < 4; nq++)
            qf[dsl][nq] = *(const short8*)&Qs[dsl][(nq * 16 + col) * 32 + qs8];

    floatx4 acc[4];
#pragma unroll
    for (int i = 0; i < 4; i++) acc[i] = (floatx4){0.f, 0.f, 0.f, 0.f};
    float esum[4] = {0.f, 0.f, 0.f, 0.f};

    // Se coalesced-store coords: thread t owns row sr=t>>2, 32B at sc0
    int sr = t >> 2;
    int sc0 = (t & 3) * 16;

    for (int kc = 0; kc < 16; kc++) {
        int cur = kc & 1;
        // ---- QK: wave w owns chunk-local keys [w*16, +16) ----
        short8 kf0 = *(const short8*)&Ks[cur][0][(w * 16 + col) * 32 + qs8];
        short8 kf1 = *(const short8*)&Ks[cur][1][(w * 16 + col) * 32 + qs8];
#pragma unroll
        for (int nq = 0; nq < 4; nq++) {
            floatx4 c = {0.f, 0.f, 0.f, 0.f};
            c = __builtin_amdgcn_mfma_f32_16x16x32_bf16(kf0, qf[0][nq], c, 0, 0, 0);
            c = __builtin_amdgcn_mfma_f32_16x16x32_bf16(kf1, qf[1][nq], c, 0, 0, 0);
            float e0 = __expf(c[0] * 0.125f);
            float e1 = __expf(c[1] * 0.125f);
            float e2 = __expf(c[2] * 0.125f);
            float e3 = __expf(c[3] * 0.125f);
            esum[nq] += (e0 + e1) + (e2 + e3);
            union { float f; u32 u; } a0, a1, a2, a3;
            a0.f = e0; a1.f = e1; a2.f = e2; a3.f = e3;
            u32* sp = (u32*)&S[nq * 16 + col][w * 16 + quad * 4];
            sp[0] = (a0.u >> 16) | (a1.u & 0xFFFF0000u);   // bf16 trunc x2
            sp[1] = (a2.u >> 16) | (a3.u & 0xFFFF0000u);
        }
        __syncthreads();   // barrier A: S complete

        // ---- coalesced Se write from LDS (for the aw pass) ----
        {
            ushort8v sa = *(const ushort8v*)&S[sr][sc0];
            ushort8v sb = *(const ushort8v*)&S[sr][sc0 + 8];
            u16* gp = Se + splane + (size_t)(q0 + sr) * CS + kc * 64 + sc0;
            *(ushort8v*)gp = sa;
            *(ushort8v*)(gp + 8) = sb;
        }

        // prefetch next K/V chunk (overlaps PV below)
        if (kc < 15) {
            int ko = (kc + 1) * 64;
            const u16* ks = ksrc0 + (size_t)ko * 1536;
            gload16(ks, Ks[cur ^ 1][0] + w * 512);
            gload16(ks + 32, Ks[cur ^ 1][1] + w * 512);
            gload16(vsrc0 + ko, Vs[cur ^ 1][0] + w * 512);
            gload16(vsrc0 + ko + 32, Vs[cur ^ 1][1] + w * 512);
        }

        // ---- PV: wave w owns q-subtile [w*16,+16), all 64 d ----
        short8 sf0 = *(const short8*)&S[w * 16 + col][quad * 8];
        short8 sf1 = *(const short8*)&S[w * 16 + col][32 + quad * 8];
#pragma unroll
        for (int nd = 0; nd < 4; nd++) {
            short8 vf0 = *(const short8*)&Vs[cur][0][(nd * 16 + col) * 32 + qs8];
            short8 vf1 = *(const short8*)&Vs[cur][1][(nd * 16 + col) * 32 + qs8];
            acc[nd] = __builtin_amdgcn_mfma_f32_16x16x32_bf16(sf0, vf0, acc[nd], 0, 0, 0);
            acc[nd] = __builtin_amdgcn_mfma_f32_16x16x32_bf16(sf1, vf1, acc[nd], 0, 0, 0);
        }
        __syncthreads();   // barrier B: S reusable; prefetch drained
    }

    // rowsums
#pragma unroll
    for (int nq = 0; nq < 4; nq++) {
        float v = esum[nq];
        v += __shfl_xor(v, 16, 64);
        v += __shfl_xor(v, 32, 64);
        if (quad == 0) rs[w][nq][col] = v;
    }
    __syncthreads();
    if (t < 64) {
        int nq = t >> 4, c2 = t & 15;
        float L = rs[0][nq][c2] + rs[1][nq][c2] + rs[2][nq][c2] + rs[3][nq][c2];
        Lout[((size_t)bh << 10) + q0 + nq * 16 + c2] = L;
    }

    // ctx: q = q0 + w*16 + quad*4 + r, d = nd*16 + col
    float li[4];
#pragma unroll
    for (int r = 0; r < 4; r++) {
        int cr = quad * 4 + r;
        li[r] = 1.0f / (rs[0][w][cr] + rs[1][w][cr] + rs[2][w][cr] + rs[3][w][cr]);
    }
    u16* cb = ctx + ((size_t)(b * CS) + q0 + w * 16 + quad * 4) * CD + h * CHD + col;
#pragma unroll
    for (int nd = 0; nd < 4; nd++)
#pragma unroll
        for (int r = 0; r < 4; r++)
            cb[(size_t)r * CD + nd * 16] = f2bf(acc[nd][r] * li[r]);
}

// ---------------------------------------------------------------------------
// attn_aw: aw[b,q,k] = (1/8) sum_h S_e[b,h,q,k] / L[b,h,q]. Pure streaming.
// ---------------------------------------------------------------------------
__global__ __launch_bounds__(256, 8) void attn_aw_kernel(
    const u16* __restrict__ Se, const float* __restrict__ Lin,
    float* __restrict__ aw_out, int b0)
{
    int bq = blockIdx.x;               // 2048: 4 b x 512 q-pairs
    int bl = bq >> 9;                  // half-local batch 0..3
    int b = b0 + bl;
    int q = (bq & 511) * 2 + (threadIdx.x >> 7);
    int k0 = (threadIdx.x & 127) * 8;

    float acc[8];
#pragma unroll
    for (int i = 0; i < 8; i++) acc[i] = 0.f;

#pragma unroll
    for (int h = 0; h < CH; h++) {
        float linv = 0.125f / Lin[(((size_t)(b * CH + h)) << 10) + q];
        const u16* sp = Se + ((size_t)(bl * CH + h) * CS + q) * CS + k0;
        ushort8v e = *(const ushort8v*)sp;
#pragma unroll
        for (int i = 0; i < 8; i++) acc[i] += bf2f(e[i]) * linv;
    }
    float* ap = aw_out + ((size_t)(b * CS) + q) * CS + k0;
    *(float4*)ap = make_float4(acc[0], acc[1], acc[2], acc[3]);
    *(float4*)(ap + 4) = make_float4(acc[4], acc[5], acc[6], acc[7]);
}

// ---------------------------------------------------------------------------
extern "C" void kernel_launch(void* const* d_in, const int* in_sizes, int n_in,
                              void* d_out, int out_size, void* d_ws, size_t ws_size,
                              hipStream_t stream)
{
    const float* x    = (const float*)d_in[0];
    const int*   ids  = (const int*)d_in[1];
    const float* emb  = (const float*)d_in[2];
    const float* inw  = (const float*)d_in[3];
    const float* inb  = (const float*)d_in[4];
    const float* ow   = (const float*)d_in[5];
    const float* ob   = (const float*)d_in[6];
    const float* g1   = (const float*)d_in[7];
    const float* be1  = (const float*)d_in[8];
    const float* g2   = (const float*)d_in[9];
    const float* be2  = (const float*)d_in[10];
    const float* w1   = (const float*)d_in[11];
    const float* b1   = (const float*)d_in[12];
    const float* w2   = (const float*)d_in[13];
    const float* b2   = (const float*)d_in[14];

    float* out_x  = (float*)d_out;
    float* out_aw = out_x + (size_t)CB * CS * CD;

    char* p = (char*)d_ws;
    float* xr   = (float*)p; p += (size_t)NROW * CD * 4;
    float* x2   = (float*)p; p += (size_t)NROW * CD * 4;
    u16* xnb    = (u16*)p;   p += (size_t)NROW * CD * 2;
    u16* qkvb   = (u16*)p;   p += (size_t)NROW * 3 * CD * 2;
    u16* ctxb   = (u16*)p;   p += (size_t)NROW * CD * 2;
    u16* hidb   = (u16*)p;   p += (size_t)NROW * CDFF * 2;
    u16* inwb   = (u16*)p;   p += (size_t)3 * CD * CD * 2;   // 4 weight buffers:
    u16* owb    = (u16*)p;   p += (size_t)CD * CD * 2;       //  contiguous (conv4)
    u16* w1b    = (u16*)p;   p += (size_t)CDFF * CD * 2;
    u16* w2b    = (u16*)p;   p += (size_t)CD * CDFF * 2;
    float* Lbuf = (float*)p; p += (size_t)CB * CH * CS * 4;   // rowsums, 256KB
    u16* Se     = (u16*)p;   p += (size_t)(CB / 2) * CH * CS * CS * 2;  // 67MB

    // vt aliases the hidb region (hidb only becomes live at step 6)
    u16* vtb = hidb;   // [b][h][64][CS], 8.4MB <= 33.6MB

    dim3 blk(256);
    // 0) weight conversions (single launch; dst regions contiguous)
    conv4_kernel<<<(3 * CD * CD + CD * CD + 2 * CDFF * CD) / 2048, blk, 0, stream>>>(
        inw, ow, w1, w2, inwb);
    // 1) x+emb, LN1 -> xr fp32, xnb bf16
    ln_kernel<<<NROW, blk, 0, stream>>>(x, ids, emb, g1, be1, xr, xnb);
    // 2) qkv projection (bf16 MFMA, bf16 out)
    gemm_mfma<0, 0, 1><<<dim3(NROW / 128, (3 * CD) / 128), blk, 0, stream>>>(
        xnb, inwb, inb, nullptr, qkvb, NROW, 3 * CD, CD);
    // 3a) V transpose
    vt_kernel<<<dim3(CB * (CS / 64), CH), blk, 0, stream>>>(qkvb, vtb);
    // 3b) fused staged attention (QK+exp+PV) + streaming aw, 2 batch-halves
    for (int half = 0; half < 2; half++) {
        int b0 = half * 4;
        attn_fused_kernel<<<512, blk, 0, stream>>>(qkvb, vtb, Se, Lbuf, ctxb, b0);
        attn_aw_kernel<<<2048, blk, 0, stream>>>(Se, Lbuf, out_aw, b0);
    }
    // 4) out projection + residual -> x2 fp32 (64x128 tiles: 512 blocks)
    gemm_mfma64<0, 1, 0><<<dim3(NROW / 64, CD / 128), blk, 0, stream>>>(
        ctxb, owb, ob, xr, x2, NROW, CD, CD);
    // 5) LN2 -> xnb bf16
    ln_kernel<<<NROW, blk, 0, stream>>>(x2, nullptr, nullptr, g2, be2, nullptr, xnb);
    // 6) FFN up + fast GELU -> hidb bf16
    gemm_mfma<1, 0, 1><<<dim3(NROW / 128, CDFF / 128), blk, 0, stream>>>(
        xnb, w1b, b1, nullptr, hidb, NROW, CDFF, CD);
    // 7) FFN down + bias + residual -> output fp32 (64x128 tiles: 512 blocks)
    gemm_mfma64<0, 1, 0><<<dim3(NROW / 64, CD / 128), blk, 0, stream>>>(
        hidb, w2b, b2, x2, out_x, NROW, CD, CDFF);
}

// Round 12
// 299.309 us; speedup vs baseline: 1.0657x; 1.0235x over previous
//
#include <hip/hip_runtime.h>
#include <math.h>

// Problem constants
constexpr int CB = 8;      // batch
constexpr int CS = 1024;   // seq
constexpr int CD = 512;    // model dim
constexpr int CH = 8;      // heads
constexpr int CHD = 64;    // head dim
constexpr int CDFF = 2048; // ffn dim
constexpr int NROW = CB * CS;

typedef unsigned short u16;
typedef unsigned int u32;
typedef __attribute__((ext_vector_type(8))) short short8;
typedef __attribute__((ext_vector_type(8))) unsigned short ushort8v;
typedef __attribute__((ext_vector_type(4))) float floatx4;

__device__ inline u16 f2bf(float f) {
    union { float f; unsigned u; } v; v.f = f;
    unsigned u = v.u + 0x7FFFu + ((v.u >> 16) & 1u);  // RNE
    return (u16)(u >> 16);
}
__device__ inline float bf2f(u16 h) {
    union { unsigned u; float f; } v; v.u = ((unsigned)h) << 16;
    return v.f;
}

// tanh-form GELU: max abs err vs exact-erf GELU ~3e-4 -> ~1e-4 at output
__device__ inline float gelu_fast(float v) {
    float u = v * (1.0f + 0.044715f * v * v);
    float e = __expf(-1.5957691216057308f * u);
    return v / (1.0f + e);
}

// async global->LDS, 16B per lane; LDS dest is wave-uniform base + lane*16.
__device__ inline void gload16(const u16* g, u16* l) {
    __builtin_amdgcn_global_load_lds(
        (const __attribute__((address_space(1))) u32*)g,
        (__attribute__((address_space(3))) u32*)l, 16, 0, 0);
}

// raw workgroup barrier with compiler memory fences (no vmcnt drain!)
__device__ inline void barrier_raw() {
    asm volatile("" ::: "memory");
    __builtin_amdgcn_s_barrier();
    asm volatile("" ::: "memory");
}

// barrier that drains LDS ops only (ds_write visibility) — no vmcnt drain
__device__ inline void barrier_lgkm() {
    asm volatile("s_waitcnt lgkmcnt(0)" ::: "memory");
    __builtin_amdgcn_s_barrier();
    asm volatile("" ::: "memory");
}

// LDS chunk-swizzle (T2, rule #21): tiles are [rows][32 elems] = 64B rows of
// four 16B chunks. Linear LDS + inverse-swizzled GLOBAL source + swizzled
// read: chunk ^= (row>>1)&3. Staging lane t covers row t>>2, so source chunk
// = (t&3) ^ ((t>>3)&3). Fragment reads at row (16a+col) use chunk
// quad ^ ((col>>1)&3). Quarter-wave -> 8 distinct 16B slots 2-way (free).
// VERIFIED R9: SQ_LDS_BANK_CONFLICT 3.1M -> 0.
#define SRC_CHUNK(t) ((((t) & 3) ^ (((t) >> 3) & 3)) * 8)

// ---------------------------------------------------------------------------
// LayerNorm (+ optional embedding add). One block per row, 256 threads.
// ---------------------------------------------------------------------------
__global__ __launch_bounds__(256) void ln_kernel(
    const float* __restrict__ x, const int* __restrict__ ids,
    const float* __restrict__ emb,
    const float* __restrict__ g, const float* __restrict__ beta,
    float* __restrict__ xr_out, u16* __restrict__ xn_out)
{
    __shared__ float red1[4], red2[4];
    __shared__ float mu_s, ri_s;
    int row = blockIdx.x;
    int tid = threadIdx.x;
    int d0 = tid * 2;
    const float* xrow = x + (size_t)row * CD;
    float2 xv = *(const float2*)(xrow + d0);
    float v0 = xv.x, v1 = xv.y;
    if (emb) {
        int id = ids[row];
        float2 ev = *(const float2*)(emb + (size_t)id * CD + d0);
        v0 += ev.x; v1 += ev.y;
    }
    float s1 = v0 + v1;
    float s2 = v0 * v0 + v1 * v1;
    for (int off = 32; off > 0; off >>= 1) {
        s1 += __shfl_down(s1, off, 64);
        s2 += __shfl_down(s2, off, 64);
    }
    int wave = tid >> 6;
    if ((tid & 63) == 0) { red1[wave] = s1; red2[wave] = s2; }
    __syncthreads();
    if (tid == 0) {
        float t1 = red1[0] + red1[1] + red1[2] + red1[3];
        float t2 = red2[0] + red2[1] + red2[2] + red2[3];
        float mu = t1 / CD;
        float var = t2 / CD - mu * mu;
        mu_s = mu;
        ri_s = rsqrtf(var + 1e-5f);
    }
    __syncthreads();
    float mu = mu_s, ri = ri_s;
    if (xr_out) {
        float2 o; o.x = v0; o.y = v1;
        *(float2*)(xr_out + (size_t)row * CD + d0) = o;
    }
    float2 gv = *(const float2*)(g + d0);
    float2 bv = *(const float2*)(beta + d0);
    float n0 = (v0 - mu) * ri * gv.x + bv.x;
    float n1 = (v1 - mu) * ri * gv.y + bv.y;
    u32 pk = (u32)f2bf(n0) | ((u32)f2bf(n1) << 16);
    *(u32*)(xn_out + (size_t)row * CD + d0) = pk;
}

// ---------------------------------------------------------------------------
// fp32 -> bf16 convert for ALL 4 weight tensors in one launch.
// ---------------------------------------------------------------------------
__global__ __launch_bounds__(256) void conv4_kernel(
    const float* __restrict__ s0, const float* __restrict__ s1,
    const float* __restrict__ s2, const float* __restrict__ s3,
    u16* __restrict__ dst)
{
    size_t i = ((size_t)blockIdx.x * 256 + threadIdx.x) * 8;
    const float* src;
    size_t off;
    if (i < 786432)        { src = s0; off = i; }
    else if (i < 1048576)  { src = s1; off = i - 786432; }
    else if (i < 2097152)  { src = s2; off = i - 1048576; }
    else                   { src = s3; off = i - 2097152; }
    float4 a = *(const float4*)(src + off);
    float4 b = *(const float4*)(src + off + 4);
    ushort8v o;
    o[0] = f2bf(a.x); o[1] = f2bf(a.y); o[2] = f2bf(a.z); o[3] = f2bf(a.w);
    o[4] = f2bf(b.x); o[5] = f2bf(b.y); o[6] = f2bf(b.z); o[7] = f2bf(b.w);
    *(ushort8v*)(dst + i) = o;
}

// ---------------------------------------------------------------------------
// bf16 MFMA GEMM, 128x128 tile. DEPTH-2 counted-vmcnt + T2 chunk-swizzle.
// ---------------------------------------------------------------------------
template <int ACT, int RES, int OUTBF>
__global__ __launch_bounds__(256) void gemm_mfma(
    const u16* __restrict__ A, const u16* __restrict__ W,
    const float* __restrict__ bias, const float* __restrict__ res,
    void* __restrict__ Cout, int M, int N, int K)
{
    __shared__ u16 As[2][128 * 32];
    __shared__ u16 Bs[2][128 * 32];
    int t = threadIdx.x;
    int lane = t & 63;
    int w = t >> 6;
    int m0 = blockIdx.x * 128;
    int n0 = blockIdx.y * 128;
    int col = lane & 15;
    int quad = lane >> 4;
    int wm = w & 1, wn = w >> 1;
    int lo = w * 512;                          // wave-local staging dest
    int qs8 = (quad ^ ((col >> 1) & 3)) * 8;   // swizzled read chunk

    const u16* ag = A + (size_t)(m0 + (t >> 2)) * K + SRC_CHUNK(t);
    const u16* ag2 = ag + (size_t)64 * K;
    const u16* bg = W + (size_t)(n0 + (t >> 2)) * K + SRC_CHUNK(t);
    const u16* bg2 = bg + (size_t)64 * K;

    // prologue: stage K-tiles 0 and 1 (8 loads/wave in flight)
#pragma unroll
    for (int i = 0; i < 2; i++) {
        gload16(ag + i * 32, As[i] + lo);
        gload16(ag2 + i * 32, As[i] + 2048 + lo);
        gload16(bg + i * 32, Bs[i] + lo);
        gload16(bg2 + i * 32, Bs[i] + 2048 + lo);
    }

    floatx4 acc[4][4];
#pragma unroll
    for (int i = 0; i < 4; i++)
#pragma unroll
        for (int j = 0; j < 4; j++) acc[i][j] = (floatx4){0.f, 0.f, 0.f, 0.f};

    int nk = K >> 5;
    for (int kt = 0; kt < nk; kt++) {
        int cur = kt & 1;
        if (kt == nk - 1) asm volatile("s_waitcnt vmcnt(0)" ::: "memory");
        else              asm volatile("s_waitcnt vmcnt(4)" ::: "memory");
        barrier_raw();      // all waves' buf[cur] slices landed
        short8 af[4], bf[4];
#pragma unroll
        for (int mi = 0; mi < 4; mi++)
            af[mi] = *(const short8*)&As[cur][(wm * 64 + mi * 16 + col) * 32 + qs8];
#pragma unroll
        for (int ni = 0; ni < 4; ni++)
            bf[ni] = *(const short8*)&Bs[cur][(wn * 64 + ni * 16 + col) * 32 + qs8];
#pragma unroll
        for (int mi = 0; mi < 4; mi++)
#pragma unroll
            for (int ni = 0; ni < 4; ni++)
                acc[mi][ni] = __builtin_amdgcn_mfma_f32_16x16x32_bf16(
                    af[mi], bf[ni], acc[mi][ni], 0, 0, 0);
        barrier_raw();      // all waves done reading buf[cur]
        if (kt + 2 < nk) {  // stage tile kt+2 into buf[cur] (just released)
            int ko = (kt + 2) * 32;
            gload16(ag + ko, As[cur] + lo);
            gload16(ag2 + ko, As[cur] + 2048 + lo);
            gload16(bg + ko, Bs[cur] + lo);
            gload16(bg2 + ko, Bs[cur] + 2048 + lo);
        }
    }

#pragma unroll
    for (int mi = 0; mi < 4; mi++)
#pragma unroll
        for (int ni = 0; ni < 4; ni++) {
            int c = n0 + wn * 64 + ni * 16 + col;
            float bv = bias[c];
#pragma unroll
            for (int r = 0; r < 4; r++) {
                int m = m0 + wm * 64 + mi * 16 + quad * 4 + r;
                float v = acc[mi][ni][r] + bv;
                if (ACT == 1) v = gelu_fast(v);
                if (RES) v += res[(size_t)m * N + c];
                if (OUTBF) ((u16*)Cout)[(size_t)m * N + c] = f2bf(v);
                else       ((float*)Cout)[(size_t)m * N + c] = v;
            }
        }
}

// ---------------------------------------------------------------------------
// bf16 MFMA GEMM, 64x128 tile. Depth-3 counted vmcnt + chunk-swizzle.
// ---------------------------------------------------------------------------
template <int ACT, int RES, int OUTBF>
__global__ __launch_bounds__(256) void gemm_mfma64(
    const u16* __restrict__ A, const u16* __restrict__ W,
    const float* __restrict__ bias, const float* __restrict__ res,
    void* __restrict__ Cout, int M, int N, int K)
{
    __shared__ u16 As[3][64 * 32];
    __shared__ u16 Bs[3][128 * 32];
    int t = threadIdx.x;
    int lane = t & 63;
    int w = t >> 6;
    int m0 = blockIdx.x * 64;
    int n0 = blockIdx.y * 128;
    int col = lane & 15;
    int quad = lane >> 4;
    int lo = w * 512;
    int qs8 = (quad ^ ((col >> 1) & 3)) * 8;

    const u16* ag = A + (size_t)(m0 + (t >> 2)) * K + SRC_CHUNK(t);
    const u16* bg = W + (size_t)(n0 + (t >> 2)) * K + SRC_CHUNK(t);
    const u16* bg2 = bg + (size_t)64 * K;

    // prologue: stage K-tiles 0,1,2 (9 loads/wave in flight)
#pragma unroll
    for (int i = 0; i < 3; i++) {
        gload16(ag + i * 32, As[i] + lo);
        gload16(bg + i * 32, Bs[i] + lo);
        gload16(bg2 + i * 32, Bs[i] + 2048 + lo);
    }

    floatx4 acc[4][2];
#pragma unroll
    for (int i = 0; i < 4; i++)
#pragma unroll
        for (int j = 0; j < 2; j++) acc[i][j] = (floatx4){0.f, 0.f, 0.f, 0.f};

    int nk = K >> 5;
    for (int kt = 0; kt < nk; kt++) {
        int cur = kt % 3;
        if (kt < nk - 2)       asm volatile("s_waitcnt vmcnt(6)" ::: "memory");
        else if (kt == nk - 2) asm volatile("s_waitcnt vmcnt(3)" ::: "memory");
        else                   asm volatile("s_waitcnt vmcnt(0)" ::: "memory");
        barrier_raw();
        short8 af[4], bf[2];
#pragma unroll
        for (int mi = 0; mi < 4; mi++)
            af[mi] = *(const short8*)&As[cur][(mi * 16 + col) * 32 + qs8];
#pragma unroll
        for (int ni = 0; ni < 2; ni++)
            bf[ni] = *(const short8*)&Bs[cur][(w * 32 + ni * 16 + col) * 32 + qs8];
#pragma unroll
        for (int mi = 0; mi < 4; mi++)
#pragma unroll
            for (int ni = 0; ni < 2; ni++)
                acc[mi][ni] = __builtin_amdgcn_mfma_f32_16x16x32_bf16(
                    af[mi], bf[ni], acc[mi][ni], 0, 0, 0);
        barrier_raw();
        if (kt + 3 < nk) {
            int ko = (kt + 3) * 32;
            gload16(ag + ko, As[cur] + lo);
            gload16(bg + ko, Bs[cur] + lo);
            gload16(bg2 + ko, Bs[cur] + 2048 + lo);
        }
    }

#pragma unroll
    for (int mi = 0; mi < 4; mi++)
#pragma unroll
        for (int ni = 0; ni < 2; ni++) {
            int c = n0 + w * 32 + ni * 16 + col;
            float bv = bias[c];
#pragma unroll
            for (int r = 0; r < 4; r++) {
                int m = m0 + mi * 16 + quad * 4 + r;
                float v = acc[mi][ni][r] + bv;
                if (ACT == 1) v = gelu_fast(v);
                if (RES) v += res[(size_t)m * N + c];
                if (OUTBF) ((u16*)Cout)[(size_t)m * N + c] = f2bf(v);
                else       ((float*)Cout)[(size_t)m * N + c] = v;
            }
        }
}

// ---------------------------------------------------------------------------
// V transpose: qkv cols 1024.. -> vt [b][h][d=64][S] (rows of S, 2KB)
// ---------------------------------------------------------------------------
__global__ __launch_bounds__(256) void vt_kernel(
    const u16* __restrict__ qkvb, u16* __restrict__ vt)
{
    __shared__ u16 tile[64][72];
    int b = blockIdx.x >> 4;
    int s0 = (blockIdx.x & 15) * 64;
    int h = blockIdx.y;
    int t = threadIdx.x;
    int r = t >> 2;
    int c0 = (t & 3) * 16;
    const u16* src = qkvb + (size_t)(b * CS + s0 + r) * 1536 + 2 * CD + h * CHD + c0;
    *(ushort8v*)&tile[r][c0] = *(const ushort8v*)src;
    *(ushort8v*)&tile[r][c0 + 8] = *(const ushort8v*)(src + 8);
    __syncthreads();
    u16* dst = vt + (((size_t)b * CH + h) * CHD + r) * CS + s0 + c0;
    ushort8v lo, hi;
#pragma unroll
    for (int j = 0; j < 8; j++) { lo[j] = tile[c0 + j][r]; hi[j] = tile[c0 + 8 + j][r]; }
    *(ushort8v*)dst = lo;
    *(ushort8v*)(dst + 8) = hi;
}

// ---------------------------------------------------------------------------
// attn_fused v2: QK + exp + PV, COUNTED-VMCNT (T4). Per 64-key chunk kc:
//   top: issue K/V[kc+1] prefetch into buf^1 (freed by prior barrier B)
//   QK from Ks[cur] -> S LDS; barrier A (lgkm only)
//   coalesced Se write from S; PV from S + Vs[cur]
//   vmcnt(2): retires the 6 prefetch loads (issued a FULL chunk ago; the 2
//   Se stores may stay in flight — in-order vmcnt retirement, m135)
//   barrier B (lgkm only). NO vmcnt(0) drain anywhere in the loop.
// nb = batches in this pass (4 or 8, runtime workspace-dependent).
// ---------------------------------------------------------------------------
__global__ __launch_bounds__(256, 2) void attn_fused_kernel(
    const u16* __restrict__ qkvb, const u16* __restrict__ vt,
    u16* __restrict__ Se, float* __restrict__ Lout,
    u16* __restrict__ ctx, int b0, int nb)
{
    __shared__ u16 Qs[2][64 * 32];      // [dsl][q][d-slice]        8 KB
    __shared__ u16 Ks[2][2][64 * 32];   // [buf][dsl][k][d-slice]  16 KB
    __shared__ u16 Vs[2][2][64 * 32];   // [buf][ksl][d][k-slice]  16 KB
    __shared__ u16 S[64][72];           // q x chunk-k (16B rows)  9.2 KB
    __shared__ float rs[4][4][16];

    int t = threadIdx.x;
    int lane = t & 63;
    int w = t >> 6;
    int col = lane & 15;
    int quad = lane >> 4;
    int qs8 = (quad ^ ((col >> 1) & 3)) * 8;   // swizzled read chunk
    int bid = blockIdx.x;           // nb*128
    int xcd = bid & 7;
    int j = bid >> 3;               // 0..nb*16-1
    int bhl = xcd * nb + (j >> 4);  // 0..nb*8-1
    int qt = j & 15;
    int lb = bhl >> 3, h = bhl & 7;
    int b = b0 + lb;
    int q0 = qt * 64;
    int bh = b * CH + h;
    size_t splane = (size_t)(lb * CH + h) * CS * CS;

    int srow = t >> 2;              // staged row 0..63
    int scol = SRC_CHUNK(t);        // pre-swizzled source chunk

    const u16* ksrc0 = qkvb + (size_t)(b * CS + srow) * 1536 + CD + h * CHD + scol;
    const u16* vsrc0 = vt + ((size_t)bh * CHD + srow) * CS + scol;

    // prologue: Q (both d-slices) + K/V chunk 0; full drain once
    {
        const u16* qsrc = qkvb + (size_t)(b * CS + q0 + srow) * 1536 + h * CHD + scol;
        gload16(qsrc, Qs[0] + w * 512);
        gload16(qsrc + 32, Qs[1] + w * 512);
        gload16(ksrc0, Ks[0][0] + w * 512);
        gload16(ksrc0 + 32, Ks[0][1] + w * 512);
        gload16(vsrc0, Vs[0][0] + w * 512);
        gload16(vsrc0 + 32, Vs[0][1] + w * 512);
    }
    __syncthreads();

    // Q fragments -> registers (static indexing; 32 VGPRs)
    short8 qf[2][4];
#pragma unroll
    for (int dsl = 0; dsl < 2; dsl++)
#pragma unroll
        for (int nq = 0; nq < 4; nq++)
            qf[dsl][nq] = *(const short8*)&Qs[dsl][(nq * 16 + col) * 32 + qs8];

    floatx4 acc[4];
#pragma unroll
    for (int i = 0; i < 4; i++) acc[i] = (floatx4){0.f, 0.f, 0.f, 0.f};
    float esum[4] = {0.f, 0.f, 0.f, 0.f};

    // Se coalesced-store coords: thread t owns row sr=t>>2, 32B at sc0
    int sr = t >> 2;
    int sc0 = (t & 3) * 16;

    for (int kc = 0; kc < 16; kc++) {
        int cur = kc & 1;
        // top: prefetch K/V[kc+1] into buf[cur^1] (readers finished at B(kc-1))
        if (kc < 15) {
            int ko = (kc + 1) * 64;
            const u16* ks = ksrc0 + (size_t)ko * 1536;
            gload16(ks, Ks[cur ^ 1][0] + w * 512);
            gload16(ks + 32, Ks[cur ^ 1][1] + w * 512);
            gload16(vsrc0 + ko, Vs[cur ^ 1][0] + w * 512);
            gload16(vsrc0 + ko + 32, Vs[cur ^ 1][1] + w * 512);
        }
        // ---- QK: wave w owns chunk-local keys [w*16, +16) ----
        short8 kf0 = *(const short8*)&Ks[cur][0][(w * 16 + col) * 32 + qs8];
        short8 kf1 = *(const short8*)&Ks[cur][1][(w * 16 + col) * 32 + qs8];
#pragma unroll
        for (int nq = 0; nq < 4; nq++) {
            floatx4 c = {0.f, 0.f, 0.f, 0.f};
            c = __builtin_amdgcn_mfma_f32_16x16x32_bf16(kf0, qf[0][nq], c, 0, 0, 0);
            c = __builtin_amdgcn_mfma_f32_16x16x32_bf16(kf1, qf[1][nq], c, 0, 0, 0);
            float e0 = __expf(c[0] * 0.125f);
            float e1 = __expf(c[1] * 0.125f);
            float e2 = __expf(c[2] * 0.125f);
            float e3 = __expf(c[3] * 0.125f);
            esum[nq] += (e0 + e1) + (e2 + e3);
            union { float f; u32 u; } a0, a1, a2, a3;
            a0.f = e0; a1.f = e1; a2.f = e2; a3.f = e3;
            u32* sp = (u32*)&S[nq * 16 + col][w * 16 + quad * 4];
            sp[0] = (a0.u >> 16) | (a1.u & 0xFFFF0000u);   // bf16 trunc x2
            sp[1] = (a2.u >> 16) | (a3.u & 0xFFFF0000u);
        }
        barrier_lgkm();    // barrier A: S writes visible to all waves

        // ---- coalesced Se write from LDS (for the aw pass): 2 stores ----
        {
            ushort8v sa = *(const ushort8v*)&S[sr][sc0];
            ushort8v sb = *(const ushort8v*)&S[sr][sc0 + 8];
            u16* gp = Se + splane + (size_t)(q0 + sr) * CS + kc * 64 + sc0;
            *(ushort8v*)gp = sa;
            *(ushort8v*)(gp + 8) = sb;
        }

        // ---- PV: wave w owns q-subtile [w*16,+16), all 64 d ----
        short8 sf0 = *(const short8*)&S[w * 16 + col][quad * 8];
        short8 sf1 = *(const short8*)&S[w * 16 + col][32 + quad * 8];
#pragma unroll
        for (int nd = 0; nd < 4; nd++) {
            short8 vf0 = *(const short8*)&Vs[cur][0][(nd * 16 + col) * 32 + qs8];
            short8 vf1 = *(const short8*)&Vs[cur][1][(nd * 16 + col) * 32 + qs8];
            acc[nd] = __builtin_amdgcn_mfma_f32_16x16x32_bf16(sf0, vf0, acc[nd], 0, 0, 0);
            acc[nd] = __builtin_amdgcn_mfma_f32_16x16x32_bf16(sf1, vf1, acc[nd], 0, 0, 0);
        }
        // retire this chunk's 6 prefetch loads (issued a full chunk ago);
        // the 2 Se stores may remain in flight (in-order retirement)
        if (kc < 15) asm volatile("s_waitcnt vmcnt(2)" ::: "memory");
        barrier_lgkm();    // barrier B: S reusable; K/V[kc+1] landed everywhere
    }

    // rowsums
#pragma unroll
    for (int nq = 0; nq < 4; nq++) {
        float v = esum[nq];
        v += __shfl_xor(v, 16, 64);
        v += __shfl_xor(v, 32, 64);
        if (quad == 0) rs[w][nq][col] = v;
    }
    __syncthreads();
    if (t < 64) {
        int nq = t >> 4, c2 = t & 15;
        float L = rs[0][nq][c2] + rs[1][nq][c2] + rs[2][nq][c2] + rs[3][nq][c2];
        Lout[((size_t)bh << 10) + q0 + nq * 16 + c2] = L;
    }

    // ctx: q = q0 + w*16 + quad*4 + r, d = nd*16 + col
    float li[4];
#pragma unroll
    for (int r = 0; r < 4; r++) {
        int cr = quad * 4 + r;
        li[r] = 1.0f / (rs[0][w][cr] + rs[1][w][cr] + rs[2][w][cr] + rs[3][w][cr]);
    }
    u16* cb = ctx + ((size_t)(b * CS) + q0 + w * 16 + quad * 4) * CD + h * CHD + col;
#pragma unroll
    for (int nd = 0; nd < 4; nd++)
#pragma unroll
        for (int r = 0; r < 4; r++)
            cb[(size_t)r * CD + nd * 16] = f2bf(acc[nd][r] * li[r]);
}

// ---------------------------------------------------------------------------
// attn_aw: aw[b,q,k] = (1/8) sum_h S_e[b,h,q,k] / L[b,h,q]. Pure streaming.
// ---------------------------------------------------------------------------
__global__ __launch_bounds__(256, 8) void attn_aw_kernel(
    const u16* __restrict__ Se, const float* __restrict__ Lin,
    float* __restrict__ aw_out, int b0, int nb)
{
    int bq = blockIdx.x;               // nb*512: nb b x 512 q-pairs
    int bl = bq >> 9;                  // pass-local batch 0..nb-1
    int b = b0 + bl;
    int q = (bq & 511) * 2 + (threadIdx.x >> 7);
    int k0 = (threadIdx.x & 127) * 8;

    float acc[8];
#pragma unroll
    for (int i = 0; i < 8; i++) acc[i] = 0.f;

#pragma unroll
    for (int h = 0; h < CH; h++) {
        float linv = 0.125f / Lin[(((size_t)(b * CH + h)) << 10) + q];
        const u16* sp = Se + ((size_t)(bl * CH + h) * CS + q) * CS + k0;
        ushort8v e = *(const ushort8v*)sp;
#pragma unroll
        for (int i = 0; i < 8; i++) acc[i] += bf2f(e[i]) * linv;
    }
    float* ap = aw_out + ((size_t)(b * CS) + q) * CS + k0;
    *(float4*)ap = make_float4(acc[0], acc[1], acc[2], acc[3]);
    *(float4*)(ap + 4) = make_float4(acc[4], acc[5], acc[6], acc[7]);
}

// ---------------------------------------------------------------------------
extern "C" void kernel_launch(void* const* d_in, const int* in_sizes, int n_in,
                              void* d_out, int out_size, void* d_ws, size_t ws_size,
                              hipStream_t stream)
{
    const float* x    = (const float*)d_in[0];
    const int*   ids  = (const int*)d_in[1];
    const float* emb  = (const float*)d_in[2];
    const float* inw  = (const float*)d_in[3];
    const float* inb  = (const float*)d_in[4];
    const float* ow   = (const float*)d_in[5];
    const float* ob   = (const float*)d_in[6];
    const float* g1   = (const float*)d_in[7];
    const float* be1  = (const float*)d_in[8];
    const float* g2   = (const float*)d_in[9];
    const float* be2  = (const float*)d_in[10];
    const float* w1   = (const float*)d_in[11];
    const float* b1   = (const float*)d_in[12];
    const float* w2   = (const float*)d_in[13];
    const float* b2   = (const float*)d_in[14];

    float* out_x  = (float*)d_out;
    float* out_aw = out_x + (size_t)CB * CS * CD;

    char* p = (char*)d_ws;
    float* xr   = (float*)p; p += (size_t)NROW * CD * 4;
    float* x2   = (float*)p; p += (size_t)NROW * CD * 4;
    u16* xnb    = (u16*)p;   p += (size_t)NROW * CD * 2;
    u16* qkvb   = (u16*)p;   p += (size_t)NROW * 3 * CD * 2;
    u16* ctxb   = (u16*)p;   p += (size_t)NROW * CD * 2;
    u16* hidb   = (u16*)p;   p += (size_t)NROW * CDFF * 2;
    u16* inwb   = (u16*)p;   p += (size_t)3 * CD * CD * 2;   // 4 weight buffers:
    u16* owb    = (u16*)p;   p += (size_t)CD * CD * 2;       //  contiguous (conv4)
    u16* w1b    = (u16*)p;   p += (size_t)CDFF * CD * 2;
    u16* w2b    = (u16*)p;   p += (size_t)CD * CDFF * 2;
    float* Lbuf = (float*)p; p += (size_t)CB * CH * CS * 4;   // rowsums, 256KB
    u16* Se     = (u16*)p;   // Se region: rest of workspace

    // single attention pass if workspace fits the full 134MB Se
    size_t base_bytes = (size_t)((char*)Se - (char*)d_ws);
    size_t se_full = (size_t)CB * CH * CS * CS * 2;
    int nb = (ws_size >= base_bytes + se_full) ? CB : (CB / 2);

    // vt aliases the hidb region (hidb only becomes live at step 6)
    u16* vtb = hidb;   // [b][h][64][CS], 8.4MB <= 33.6MB

    dim3 blk(256);
    // 0) weight conversions (single launch; dst regions contiguous)
    conv4_kernel<<<(3 * CD * CD + CD * CD + 2 * CDFF * CD) / 2048, blk, 0, stream>>>(
        inw, ow, w1, w2, inwb);
    // 1) x+emb, LN1 -> xr fp32, xnb bf16
    ln_kernel<<<NROW, blk, 0, stream>>>(x, ids, emb, g1, be1, xr, xnb);
    // 2) qkv projection (bf16 MFMA, bf16 out)
    gemm_mfma<0, 0, 1><<<dim3(NROW / 128, (3 * CD) / 128), blk, 0, stream>>>(
        xnb, inwb, inb, nullptr, qkvb, NROW, 3 * CD, CD);
    // 3a) V transpose
    vt_kernel<<<dim3(CB * (CS / 64), CH), blk, 0, stream>>>(qkvb, vtb);
    // 3b) fused counted-vmcnt attention (QK+exp+PV) + streaming aw
    for (int b0 = 0; b0 < CB; b0 += nb) {
        attn_fused_kernel<<<nb * 128, blk, 0, stream>>>(
            qkvb, vtb, Se, Lbuf, ctxb, b0, nb);
        attn_aw_kernel<<<nb * 512, blk, 0, stream>>>(Se, Lbuf, out_aw, b0, nb);
    }
    // 4) out projection + residual -> x2 fp32 (64x128 tiles: 512 blocks)
    gemm_mfma64<0, 1, 0><<<dim3(NROW / 64, CD / 128), blk, 0, stream>>>(
        ctxb, owb, ob, xr, x2, NROW, CD, CD);
    // 5) LN2 -> xnb bf16
    ln_kernel<<<NROW, blk, 0, stream>>>(x2, nullptr, nullptr, g2, be2, nullptr, xnb);
    // 6) FFN up + fast GELU -> hidb bf16
    gemm_mfma<1, 0, 1><<<dim3(NROW / 128, CDFF / 128), blk, 0, stream>>>(
        xnb, w1b, b1, nullptr, hidb, NROW, CDFF, CD);
    // 7) FFN down + bias + residual -> output fp32 (64x128 tiles: 512 blocks)
    gemm_mfma64<0, 1, 0><<<dim3(NROW / 64, CD / 128), blk, 0, stream>>>(
        hidb, w2b, b2, x2, out_x, NROW, CD, CDFF);
}